// Round 2
// baseline (2513.246 us; speedup 1.0000x reference)
//
#include <hip/hip_runtime.h>

#define S 1024
#define MDIM 1024
#define NH 16
#define HD 64
#define NKV 8
#define FF 3072
#define NE 64
#define TOPK 8
#define CAP 256

typedef unsigned short u16;
typedef __attribute__((ext_vector_type(8))) short bf16x8;
typedef __attribute__((ext_vector_type(4))) float f32x4;

__device__ __forceinline__ u16 f2bf(float f) {
    union { float f; unsigned u; } x; x.f = f;
    unsigned r = x.u + 0x7FFFu + ((x.u >> 16) & 1u);
    return (u16)(r >> 16);
}
__device__ __forceinline__ float bf2f(u16 b) {
    union { unsigned u; float f; } x; x.u = ((unsigned)b) << 16;
    return x.f;
}
// split f32 -> bf16 hi + bf16 lo (x ~= hi + lo, error ~2^-18 rel)
__device__ __forceinline__ void split1(float x, u16& h, u16& l) {
    h = f2bf(x);
    l = f2bf(x - bf2f(h));
}
__device__ __forceinline__ void split8(const float* __restrict__ p, bf16x8& hi, bf16x8& lo) {
    f32x4 a = *(const f32x4*)p;
    f32x4 b = *(const f32x4*)(p + 4);
#pragma unroll
    for (int i = 0; i < 4; ++i) {
        u16 h, l;
        split1(a[i], h, l); hi[i] = (short)h; lo[i] = (short)l;
        split1(b[i], h, l); hi[i + 4] = (short)h; lo[i + 4] = (short)l;
    }
}

// ---------------- RMS norm (row of 1024), f32 out ----------------
__global__ __launch_bounds__(256) void k_rms(const float* __restrict__ x,
                                             const float* __restrict__ w,
                                             float* __restrict__ o) {
    int s = blockIdx.x;
    const float* row = x + (size_t)s * MDIM;
    float v[4]; float ss = 0.f;
#pragma unroll
    for (int i = 0; i < 4; ++i) { v[i] = row[threadIdx.x + i * 256]; ss += v[i] * v[i]; }
#pragma unroll
    for (int of = 32; of; of >>= 1) ss += __shfl_xor(ss, of);
    __shared__ float red[4];
    int wid = threadIdx.x >> 6;
    if ((threadIdx.x & 63) == 0) red[wid] = ss;
    __syncthreads();
    float tot = red[0] + red[1] + red[2] + red[3];
    float sc = rsqrtf(tot * (1.f / MDIM) + 1e-6f);
#pragma unroll
    for (int i = 0; i < 4; ++i) {
        int c = threadIdx.x + i * 256;
        o[(size_t)s * MDIM + c] = v[i] * sc * w[c];
    }
}

// ---------------- split-bf16 MFMA GEMM: C[M,N] = A(f32,[M,K]) @ B(f32,[K,N]) ----------------
// EPI: 0 = f32 out (e-strided), 1 = f32 out + resid, 2 = swiglu pair -> f32 out (e-strided)
// ASPLIT: 3-term (A hi/lo) vs 2-term (A plain bf16). B always split.
template <int TM, int EPI, bool ASPLIT>
__global__ __launch_bounds__(256) void k_gemm(
    const float* __restrict__ A, int lda, long sAe,
    const float* __restrict__ B, int ldb, long sBe,
    void* __restrict__ Cv, int ldc, long sCe,
    const float* __restrict__ resid,
    int M, int K, int pairOff, const int* __restrict__ counts,
    const int* __restrict__ rowidx) {
    int e = blockIdx.z;
    if (counts) M = counts[e];
    int m0 = blockIdx.y * TM;
    if (m0 >= M) return;
    A += (size_t)e * sAe;
    B += (size_t)e * sBe;
    int n0 = blockIdx.x * 64;

    __shared__ u16 Ah[TM][40];
    __shared__ u16 Al[ASPLIT ? TM : 1][40];
    __shared__ u16 Bh[64][40];
    __shared__ u16 Bl[64][40];
    __shared__ u16 B2h[EPI == 2 ? 64 : 1][40];
    __shared__ u16 B2l[EPI == 2 ? 64 : 1][40];

    int tid = threadIdx.x;
    int lane = tid & 63, wid = tid >> 6;
    constexpr int MF = TM / 32;
    int wm = (wid >> 1) * (TM / 2), wn = (wid & 1) * 32;

    f32x4 acc[MF][2] = {};
    f32x4 acc2[EPI == 2 ? MF : 1][2] = {};

    for (int k0 = 0; k0 < K; k0 += 32) {
        // stage A tile (TM x 32) f32 -> bf16 hi(/lo)
#pragma unroll
        for (int rr = 0; rr < TM / 64; ++rr) {
            int r = rr * 64 + (tid >> 2);
            int c = (tid & 3) * 8;
            int gm = m0 + r;
            float xv[8];
            if (gm < M) {
                int asrc = rowidx ? rowidx[e * CAP + gm] : gm;
                const float* ap = A + (size_t)asrc * lda + k0 + c;
                f32x4 v0 = *(const f32x4*)ap;
                f32x4 v1 = *(const f32x4*)(ap + 4);
#pragma unroll
                for (int i = 0; i < 4; ++i) { xv[i] = v0[i]; xv[i + 4] = v1[i]; }
            } else {
#pragma unroll
                for (int i = 0; i < 8; ++i) xv[i] = 0.f;
            }
#pragma unroll
            for (int i = 0; i < 8; ++i) {
                u16 h = f2bf(xv[i]);
                Ah[r][c + i] = h;
                if constexpr (ASPLIT) Al[r][c + i] = f2bf(xv[i] - bf2f(h));
            }
        }
        // stage B tile (32 x 64) f32 -> bf16 hi/lo, transposed into [n][k]
        {
            int n = tid & 63, kb = tid >> 6;
#pragma unroll
            for (int i = 0; i < 8; ++i) {
                int kk = kb + i * 4;
                u16 h, l;
                split1(B[(size_t)(k0 + kk) * ldb + n0 + n], h, l);
                Bh[n][kk] = h; Bl[n][kk] = l;
                if constexpr (EPI == 2) {
                    split1(B[(size_t)(k0 + kk) * ldb + n0 + pairOff + n], h, l);
                    B2h[n][kk] = h; B2l[n][kk] = l;
                }
            }
        }
        __syncthreads();
        bf16x8 ah[MF], al[ASPLIT ? MF : 1], bh[2], bl[2];
#pragma unroll
        for (int mi = 0; mi < MF; ++mi) {
            ah[mi] = *(const bf16x8*)&Ah[wm + mi * 16 + (lane & 15)][(lane >> 4) * 8];
            if constexpr (ASPLIT) al[mi] = *(const bf16x8*)&Al[wm + mi * 16 + (lane & 15)][(lane >> 4) * 8];
        }
#pragma unroll
        for (int ni = 0; ni < 2; ++ni) {
            bh[ni] = *(const bf16x8*)&Bh[wn + ni * 16 + (lane & 15)][(lane >> 4) * 8];
            bl[ni] = *(const bf16x8*)&Bl[wn + ni * 16 + (lane & 15)][(lane >> 4) * 8];
        }
#pragma unroll
        for (int mi = 0; mi < MF; ++mi)
#pragma unroll
            for (int ni = 0; ni < 2; ++ni) {
                acc[mi][ni] = __builtin_amdgcn_mfma_f32_16x16x32_bf16(ah[mi], bh[ni], acc[mi][ni], 0, 0, 0);
                acc[mi][ni] = __builtin_amdgcn_mfma_f32_16x16x32_bf16(ah[mi], bl[ni], acc[mi][ni], 0, 0, 0);
                if constexpr (ASPLIT)
                    acc[mi][ni] = __builtin_amdgcn_mfma_f32_16x16x32_bf16(al[mi], bh[ni], acc[mi][ni], 0, 0, 0);
            }
        if constexpr (EPI == 2) {
            bf16x8 gh[2], gl[2];
#pragma unroll
            for (int ni = 0; ni < 2; ++ni) {
                gh[ni] = *(const bf16x8*)&B2h[wn + ni * 16 + (lane & 15)][(lane >> 4) * 8];
                gl[ni] = *(const bf16x8*)&B2l[wn + ni * 16 + (lane & 15)][(lane >> 4) * 8];
            }
#pragma unroll
            for (int mi = 0; mi < MF; ++mi)
#pragma unroll
                for (int ni = 0; ni < 2; ++ni) {
                    acc2[mi][ni] = __builtin_amdgcn_mfma_f32_16x16x32_bf16(ah[mi], gh[ni], acc2[mi][ni], 0, 0, 0);
                    acc2[mi][ni] = __builtin_amdgcn_mfma_f32_16x16x32_bf16(ah[mi], gl[ni], acc2[mi][ni], 0, 0, 0);
                    if constexpr (ASPLIT)
                        acc2[mi][ni] = __builtin_amdgcn_mfma_f32_16x16x32_bf16(al[mi], gh[ni], acc2[mi][ni], 0, 0, 0);
                }
        }
        __syncthreads();
    }
    // epilogue: D row = (lane>>4)*4 + r, col = lane&15
#pragma unroll
    for (int mi = 0; mi < MF; ++mi)
#pragma unroll
        for (int ni = 0; ni < 2; ++ni)
#pragma unroll
            for (int r = 0; r < 4; ++r) {
                int row = m0 + wm + mi * 16 + (lane >> 4) * 4 + r;
                int col = n0 + wn + ni * 16 + (lane & 15);
                if (row >= M) continue;
                float v = acc[mi][ni][r];
                if constexpr (EPI == 0) {
                    ((float*)Cv)[(size_t)e * sCe + (size_t)row * ldc + col] = v;
                } else if constexpr (EPI == 1) {
                    ((float*)Cv)[(size_t)row * ldc + col] = v + resid[(size_t)row * ldc + col];
                } else {
                    float x2 = acc2[mi][ni][r];
                    float val = v * (x2 / (1.f + __expf(-x2)));
                    ((float*)Cv)[(size_t)e * sCe + (size_t)row * ldc + col] = val;
                }
            }
}

// ---------------- unpack QKV + RoPE + q/k RMS norm -> f32 q/k/v ----------------
__global__ __launch_bounds__(256) void k_rope(const float* __restrict__ qkv,
                                              const float* __restrict__ cosb,
                                              const float* __restrict__ sinb,
                                              const float* __restrict__ qn_w,
                                              const float* __restrict__ kn_w,
                                              float* __restrict__ qo,
                                              float* __restrict__ ko,
                                              float* __restrict__ vo) {
    int wid = threadIdx.x >> 6, lane = threadIdx.x & 63;
    int idx = blockIdx.x * 4 + wid;   // 0..8191
    int s = idx >> 3, j = idx & 7;
    const float* base = qkv + (size_t)s * 2048 + j * 256;
    float c = cosb[s * HD + lane], sn = sinb[s * HD + lane];
    vo[((size_t)j * S + s) * HD + lane] = base[192 + lane];
#pragma unroll
    for (int r = 0; r < 3; ++r) {
        float x = base[r * 64 + lane];
        float xp = __shfl_xor(x, 32);
        float rot = (lane < 32) ? -xp : xp;
        float y = x * c + rot * sn;
        float ss = y * y;
#pragma unroll
        for (int o = 32; o; o >>= 1) ss += __shfl_xor(ss, o);
        float scale = rsqrtf(ss * (1.f / 64.f) + 1e-6f);
        float outv = y * scale * ((r == 2) ? kn_w[lane] : qn_w[lane]);
        if (r == 2) ko[((size_t)j * S + s) * HD + lane] = outv;
        else qo[((size_t)(j * 2 + r) * S + s) * HD + lane] = outv;
    }
}

// ---------------- attention scores: S = Q @ K^T * 0.125 (lower-triangle tiles), split-bf16 ----------------
__global__ __launch_bounds__(256) void k_scores(const float* __restrict__ q,
                                                const float* __restrict__ kmat,
                                                float* __restrict__ scores) {
    int kt = blockIdx.x, qt = blockIdx.y, h = blockIdx.z;
    if (kt > qt) return;
    const float* Q = q + (size_t)h * S * HD;
    const float* Kb = kmat + (size_t)(h >> 1) * S * HD;
    int lane = threadIdx.x & 63, wid = threadIdx.x >> 6;
    int wq = (wid >> 1) * 32, wk = (wid & 1) * 32;
    int q0 = qt * 64, k0 = kt * 64;
    f32x4 acc[2][2] = {};
#pragma unroll
    for (int ks = 0; ks < 2; ++ks) {
        bf16x8 ah[2], al[2], bh[2], bl[2];
#pragma unroll
        for (int mi = 0; mi < 2; ++mi)
            split8(Q + (size_t)(q0 + wq + mi * 16 + (lane & 15)) * HD + ks * 32 + (lane >> 4) * 8, ah[mi], al[mi]);
#pragma unroll
        for (int ni = 0; ni < 2; ++ni)
            split8(Kb + (size_t)(k0 + wk + ni * 16 + (lane & 15)) * HD + ks * 32 + (lane >> 4) * 8, bh[ni], bl[ni]);
#pragma unroll
        for (int mi = 0; mi < 2; ++mi)
#pragma unroll
            for (int ni = 0; ni < 2; ++ni) {
                acc[mi][ni] = __builtin_amdgcn_mfma_f32_16x16x32_bf16(ah[mi], bh[ni], acc[mi][ni], 0, 0, 0);
                acc[mi][ni] = __builtin_amdgcn_mfma_f32_16x16x32_bf16(ah[mi], bl[ni], acc[mi][ni], 0, 0, 0);
                acc[mi][ni] = __builtin_amdgcn_mfma_f32_16x16x32_bf16(al[mi], bh[ni], acc[mi][ni], 0, 0, 0);
            }
    }
#pragma unroll
    for (int mi = 0; mi < 2; ++mi)
#pragma unroll
        for (int ni = 0; ni < 2; ++ni)
#pragma unroll
            for (int r = 0; r < 4; ++r) {
                int row = q0 + wq + mi * 16 + (lane >> 4) * 4 + r;
                int col = k0 + wk + ni * 16 + (lane & 15);
                scores[(size_t)h * S * S + (size_t)row * S + col] = acc[mi][ni][r] * 0.125f;
            }
}

// ---------------- causal softmax, one wave per row, in-place f32 ----------------
__global__ __launch_bounds__(256) void k_softmax(float* __restrict__ scores) {
    int wid = threadIdx.x >> 6, lane = threadIdx.x & 63;
    int q = blockIdx.x * 4 + wid, h = blockIdx.y;
    float* row = scores + (size_t)h * S * S + (size_t)q * S;
    int L = q + 1;
    float v[16];
    float mx = -1e30f;
#pragma unroll
    for (int i = 0; i < 16; ++i) {
        int idx = lane + i * 64;
        v[i] = (idx < L) ? row[idx] : -1e30f;
        mx = fmaxf(mx, v[i]);
    }
#pragma unroll
    for (int o = 32; o; o >>= 1) mx = fmaxf(mx, __shfl_xor(mx, o));
    float sum = 0.f;
#pragma unroll
    for (int i = 0; i < 16; ++i) {
        int idx = lane + i * 64;
        v[i] = (idx < L) ? __expf(v[i] - mx) : 0.f;
        sum += v[i];
    }
#pragma unroll
    for (int o = 32; o; o >>= 1) sum += __shfl_xor(sum, o);
    float inv = 1.f / sum;
#pragma unroll
    for (int i = 0; i < 16; ++i) row[lane + i * 64] = v[i] * inv;
}

// ---------------- O = P @ V (split-bf16), writes ao f32 in (s, h*64+d) layout ----------------
__global__ __launch_bounds__(256) void k_pv(const float* __restrict__ P,
                                            const float* __restrict__ vmat,
                                            float* __restrict__ ao) {
    int qt = blockIdx.x, h = blockIdx.y;
    const float* Pb = P + (size_t)h * S * S;
    const float* Vb = vmat + (size_t)(h >> 1) * S * HD;
    __shared__ u16 Vh[64][72];
    __shared__ u16 Vl[64][72];
    int tid = threadIdx.x, lane = tid & 63, wid = tid >> 6;
    int wq = (wid >> 1) * 32, wd = (wid & 1) * 32;
    int q0 = qt * 64;
    f32x4 acc[2][2] = {};
    int kmax = (qt + 1) * 64;
    for (int kc = 0; kc < kmax; kc += 64) {
#pragma unroll
        for (int i = 0; i < 16; ++i) {
            int idx = tid + i * 256;
            int kr = idx >> 6, d = idx & 63;
            u16 hh, ll;
            split1(Vb[(size_t)(kc + kr) * HD + d], hh, ll);
            Vh[d][kr] = hh; Vl[d][kr] = ll;
        }
        __syncthreads();
#pragma unroll
        for (int ks = 0; ks < 2; ++ks) {
            bf16x8 ph[2], pl[2], vh[2], vl[2];
#pragma unroll
            for (int mi = 0; mi < 2; ++mi)
                split8(Pb + (size_t)(q0 + wq + mi * 16 + (lane & 15)) * S + kc + ks * 32 + (lane >> 4) * 8,
                       ph[mi], pl[mi]);
#pragma unroll
            for (int ni = 0; ni < 2; ++ni) {
                vh[ni] = *(const bf16x8*)&Vh[wd + ni * 16 + (lane & 15)][ks * 32 + (lane >> 4) * 8];
                vl[ni] = *(const bf16x8*)&Vl[wd + ni * 16 + (lane & 15)][ks * 32 + (lane >> 4) * 8];
            }
#pragma unroll
            for (int mi = 0; mi < 2; ++mi)
#pragma unroll
                for (int ni = 0; ni < 2; ++ni) {
                    acc[mi][ni] = __builtin_amdgcn_mfma_f32_16x16x32_bf16(ph[mi], vh[ni], acc[mi][ni], 0, 0, 0);
                    acc[mi][ni] = __builtin_amdgcn_mfma_f32_16x16x32_bf16(ph[mi], vl[ni], acc[mi][ni], 0, 0, 0);
                    acc[mi][ni] = __builtin_amdgcn_mfma_f32_16x16x32_bf16(pl[mi], vh[ni], acc[mi][ni], 0, 0, 0);
                }
        }
        __syncthreads();
    }
#pragma unroll
    for (int mi = 0; mi < 2; ++mi)
#pragma unroll
        for (int ni = 0; ni < 2; ++ni)
#pragma unroll
            for (int r = 0; r < 4; ++r) {
                int row = q0 + wq + mi * 16 + (lane >> 4) * 4 + r;
                int col = wd + ni * 16 + (lane & 15);
                ao[(size_t)row * MDIM + h * HD + col] = acc[mi][ni][r];
            }
}

// ---------------- router logits (f32): logits = h2 @ gate_w ----------------
__global__ __launch_bounds__(256) void k_logits(const float* __restrict__ h2,
                                                const float* __restrict__ gw,
                                                float* __restrict__ logits) {
    __shared__ float xr[1024];
    __shared__ float part[4][64];
    int s = blockIdx.x;
#pragma unroll
    for (int i = 0; i < 4; ++i) xr[threadIdx.x + i * 256] = h2[(size_t)s * MDIM + threadIdx.x + i * 256];
    __syncthreads();
    int e = threadIdx.x & 63, qq = threadIdx.x >> 6;
    float acc = 0.f;
    for (int i = 0; i < 256; ++i) acc += xr[qq * 256 + i] * gw[(size_t)(qq * 256 + i) * NE + e];
    part[qq][e] = acc;
    __syncthreads();
    if (threadIdx.x < 64)
        logits[(size_t)s * NE + threadIdx.x] =
            part[0][threadIdx.x] + part[1][threadIdx.x] + part[2][threadIdx.x] + part[3][threadIdx.x];
}

// ---------------- softmax + top-8 (tie -> lowest index, like lax.top_k) ----------------
__global__ __launch_bounds__(256) void k_topk(const float* __restrict__ logits,
                                              int* __restrict__ topi,
                                              float* __restrict__ wts) {
    int wid = threadIdx.x >> 6, lane = threadIdx.x & 63;
    int s = blockIdx.x * 4 + wid;
    float lg = logits[(size_t)s * NE + lane];
    float mx = lg;
#pragma unroll
    for (int o = 32; o; o >>= 1) mx = fmaxf(mx, __shfl_xor(mx, o));
    float ex = __expf(lg - mx);
    float sum = ex;
#pragma unroll
    for (int o = 32; o; o >>= 1) sum += __shfl_xor(sum, o);
    float g = ex / sum;
    float cur = g;
    float tv[TOPK]; int ti[TOPK];
    float tsum = 0.f;
#pragma unroll
    for (int k = 0; k < TOPK; ++k) {
        float v = cur; int ii = lane;
#pragma unroll
        for (int o = 32; o; o >>= 1) {
            float vo = __shfl_xor(v, o);
            int io = __shfl_xor(ii, o);
            if (vo > v || (vo == v && io < ii)) { v = vo; ii = io; }
        }
        tv[k] = v; ti[k] = ii; tsum += v;
        if (lane == ii) cur = -1.f;
    }
    float gs = fmaxf(tsum, 1.1920929e-07f);
    if (lane == 0) {
#pragma unroll
        for (int k = 0; k < TOPK; ++k) {
            topi[s * TOPK + k] = ti[k];
            wts[s * TOPK + k] = tv[k] / gs;
        }
    }
}

// ---------------- exact rank-major priority / capacity assignment ----------------
__global__ void k_slots(const int* __restrict__ topi, int* __restrict__ slots,
                        int* __restrict__ counts, int* __restrict__ etok) {
    int e = threadIdx.x;  // 64 threads, one per expert
    int cnt = 0;
    for (int k = 0; k < TOPK; ++k)
        for (int s = 0; s < S; ++s)
            if (topi[s * TOPK + k] == e) {
                if (cnt < CAP) { slots[s * TOPK + k] = cnt; etok[e * CAP + cnt] = s; }
                else slots[s * TOPK + k] = -1;
                cnt++;
            }
    counts[e] = cnt < CAP ? cnt : CAP;
}

// ---------------- final combine: out = h + shared + sum_k w_k * eo[e_k, slot_k] ----------------
__global__ __launch_bounds__(256) void k_combine(const float* __restrict__ h,
                                                 const float* __restrict__ sh,
                                                 const float* __restrict__ eo,
                                                 const int* __restrict__ topi,
                                                 const int* __restrict__ slots,
                                                 const float* __restrict__ wts,
                                                 float* __restrict__ out) {
    int s = blockIdx.x, t = threadIdx.x;
    float w[TOPK]; int off[TOPK];
#pragma unroll
    for (int k = 0; k < TOPK; ++k) {
        int sl = slots[s * TOPK + k];
        int ee = topi[s * TOPK + k];
        w[k] = wts[s * TOPK + k];
        off[k] = (sl >= 0) ? ee * CAP + sl : -1;
    }
#pragma unroll
    for (int i = 0; i < 4; ++i) {
        int col = t + i * 256;
        float acc = h[(size_t)s * MDIM + col] + sh[(size_t)s * MDIM + col];
#pragma unroll
        for (int k = 0; k < TOPK; ++k)
            if (off[k] >= 0) acc += w[k] * eo[(size_t)off[k] * MDIM + col];
        out[(size_t)s * MDIM + col] = acc;
    }
}

extern "C" void kernel_launch(void* const* d_in, const int* in_sizes, int n_in,
                              void* d_out, int out_size, void* d_ws, size_t ws_size,
                              hipStream_t stream) {
    (void)in_sizes; (void)n_in; (void)out_size; (void)ws_size;
    const float* hidden = (const float*)d_in[0];
    const float* cosb   = (const float*)d_in[1];
    const float* sinb   = (const float*)d_in[2];
    const float* ln1_w  = (const float*)d_in[3];
    const float* ln2_w  = (const float*)d_in[4];
    const float* qkv_w  = (const float*)d_in[5];
    const float* o_w    = (const float*)d_in[6];
    const float* qn_w   = (const float*)d_in[7];
    const float* kn_w   = (const float*)d_in[8];
    const float* sgu_w  = (const float*)d_in[9];
    const float* sdn_w  = (const float*)d_in[10];
    const float* gate_w = (const float*)d_in[11];
    const float* egu_w  = (const float*)d_in[12];
    const float* edn_w  = (const float*)d_in[13];
    float* out = (float*)d_out;

    char* ws = (char*)d_ws;
    size_t off = 0;
    auto alloc = [&](size_t bytes) -> void* {
        void* p = ws + off;
        off = (off + bytes + 255) & ~(size_t)255;
        return p;
    };
    float* hnf     = (float*)alloc((size_t)S * MDIM * 4);
    float* qkvb    = (float*)alloc((size_t)S * 2048 * 4);
    float* qf      = (float*)alloc((size_t)NH * S * HD * 4);
    float* kf      = (float*)alloc((size_t)NKV * S * HD * 4);
    float* vf      = (float*)alloc((size_t)NKV * S * HD * 4);
    float* scores  = (float*)alloc((size_t)NH * S * S * 4);   // reused in-place as P
    float* aof     = (float*)alloc((size_t)S * MDIM * 4);
    float* hbuf    = (float*)alloc((size_t)S * MDIM * 4);
    float* h2f     = (float*)alloc((size_t)S * MDIM * 4);
    float* gatedS  = (float*)alloc((size_t)S * FF * 4);
    float* sharedO = (float*)alloc((size_t)S * MDIM * 4);
    float* logits  = (float*)alloc((size_t)S * NE * 4);
    int*   topi    = (int*)  alloc((size_t)S * TOPK * 4);
    float* wts     = (float*)alloc((size_t)S * TOPK * 4);
    int*   slots   = (int*)  alloc((size_t)S * TOPK * 4);
    int*   counts  = (int*)  alloc((size_t)NE * 4);
    int*   etok    = (int*)  alloc((size_t)NE * CAP * 4);
    float* egated  = (float*)alloc((size_t)NE * CAP * FF * 4);
    float* eo      = (float*)alloc((size_t)NE * CAP * MDIM * 4);

    // 1. RMS norm 1 -> hn (f32)
    k_rms<<<dim3(S), 256, 0, stream>>>(hidden, ln1_w, hnf);
    // 2. QKV projection (3-term split): (S,1024) @ (1024,2048) -> f32
    k_gemm<64, 0, true><<<dim3(2048 / 64, S / 64, 1), 256, 0, stream>>>(
        hnf, MDIM, 0, qkv_w, 2048, 0, qkvb, 2048, 0, nullptr, S, MDIM, 0, nullptr, nullptr);
    // 3. unpack + RoPE + q/k RMS -> f32
    k_rope<<<dim3(S * NKV / 4), 256, 0, stream>>>(qkvb, cosb, sinb, qn_w, kn_w, qf, kf, vf);
    // 4. scores (lower triangle, 3-term split)
    k_scores<<<dim3(16, 16, NH), 256, 0, stream>>>(qf, kf, scores);
    // 5. causal softmax in-place f32
    k_softmax<<<dim3(S / 4, NH), 256, 0, stream>>>(scores);
    // 6. P @ V -> ao f32 (3-term split)
    k_pv<<<dim3(16, NH), 256, 0, stream>>>(scores, vf, aof);
    // 7. O projection + residual -> h f32 (3-term split)
    k_gemm<64, 1, true><<<dim3(MDIM / 64, S / 64, 1), 256, 0, stream>>>(
        aof, MDIM, 0, o_w, MDIM, 0, hbuf, MDIM, 0, hidden, S, MDIM, 0, nullptr, nullptr);
    // 8. RMS norm 2 -> h2 (f32)
    k_rms<<<dim3(S), 256, 0, stream>>>(hbuf, ln2_w, h2f);
    // 9. router logits (f32)
    k_logits<<<dim3(S), 256, 0, stream>>>(h2f, gate_w, logits);
    // 10. softmax + top-8
    k_topk<<<dim3(S / 4), 256, 0, stream>>>(logits, topi, wts);
    // 11. capacity / slot assignment (exact reference semantics)
    k_slots<<<dim3(1), 64, 0, stream>>>(topi, slots, counts, etok);
    // 12. shared MLP up+gate (fused swiglu, 2-term) -> gatedS f32
    k_gemm<64, 2, false><<<dim3(FF / 64, S / 64, 1), 256, 0, stream>>>(
        h2f, MDIM, 0, sgu_w, 2 * FF, 0, gatedS, FF, 0, nullptr, S, MDIM, FF, nullptr, nullptr);
    // 13. shared MLP down (2-term) -> sharedO f32
    k_gemm<64, 0, false><<<dim3(MDIM / 64, S / 64, 1), 256, 0, stream>>>(
        gatedS, FF, 0, sdn_w, MDIM, 0, sharedO, MDIM, 0, nullptr, S, FF, 0, nullptr, nullptr);
    // 14. expert up+gate (fused swiglu, 2-term, gather-on-the-fly), batched over experts
    k_gemm<128, 2, false><<<dim3(FF / 64, CAP / 128, NE), 256, 0, stream>>>(
        h2f, MDIM, 0, egu_w, 2 * FF, (long)MDIM * 2 * FF,
        egated, FF, (long)CAP * FF, nullptr, CAP, MDIM, FF, counts, etok);
    // 15. expert down (2-term) -> eo f32, batched
    k_gemm<128, 0, false><<<dim3(MDIM / 64, CAP / 128, NE), 256, 0, stream>>>(
        egated, FF, (long)CAP * FF, edn_w, MDIM, (long)FF * MDIM,
        eo, MDIM, (long)CAP * MDIM, nullptr, CAP, FF, 0, counts, nullptr);
    // 16. combine: out = h + shared + moe
    k_combine<<<dim3(S), 256, 0, stream>>>(hbuf, sharedO, eo, topi, slots, wts, out);
}

// Round 3
// 1515.639 us; speedup vs baseline: 1.6582x; 1.6582x over previous
//
#include <hip/hip_runtime.h>

#define S 1024
#define MDIM 1024
#define NH 16
#define HD 64
#define NKV 8
#define FF 3072
#define NE 64
#define TOPK 8
#define CAP 256

typedef unsigned short u16;
typedef __attribute__((ext_vector_type(8))) short bf16x8;
typedef __attribute__((ext_vector_type(4))) float f32x4;

__device__ __forceinline__ u16 f2bf(float f) {
    union { float f; unsigned u; } x; x.f = f;
    unsigned r = x.u + 0x7FFFu + ((x.u >> 16) & 1u);
    return (u16)(r >> 16);
}
__device__ __forceinline__ float bf2f(u16 b) {
    union { unsigned u; float f; } x; x.u = ((unsigned)b) << 16;
    return x.f;
}
__device__ __forceinline__ void split1(float x, u16& h, u16& l) {
    h = f2bf(x);
    l = f2bf(x - bf2f(h));
}

// ---------------- RMS norm (row of 1024), f32 out + optional bf16 out ----------------
__global__ __launch_bounds__(256) void k_rms(const float* __restrict__ x,
                                             const float* __restrict__ w,
                                             float* __restrict__ o,
                                             u16* __restrict__ obf) {
    int s = blockIdx.x;
    const float* row = x + (size_t)s * MDIM;
    float v[4]; float ss = 0.f;
#pragma unroll
    for (int i = 0; i < 4; ++i) { v[i] = row[threadIdx.x + i * 256]; ss += v[i] * v[i]; }
#pragma unroll
    for (int of = 32; of; of >>= 1) ss += __shfl_xor(ss, of);
    __shared__ float red[4];
    int wid = threadIdx.x >> 6;
    if ((threadIdx.x & 63) == 0) red[wid] = ss;
    __syncthreads();
    float tot = red[0] + red[1] + red[2] + red[3];
    float sc = rsqrtf(tot * (1.f / MDIM) + 1e-6f);
#pragma unroll
    for (int i = 0; i < 4; ++i) {
        int c = threadIdx.x + i * 256;
        float ov = v[i] * sc * w[c];
        o[(size_t)s * MDIM + c] = ov;
        if (obf) obf[(size_t)s * MDIM + c] = f2bf(ov);
    }
}

// ---------------- 3-term split GEMM (routing-critical path): C = A(f32)@B(f32) ----------------
// EPI: 0 = f32 out, 1 = f32 out + resid
template <int EPI>
__global__ __launch_bounds__(256) void k_gemm_split(
    const float* __restrict__ A, int lda,
    const float* __restrict__ B, int ldb,
    float* __restrict__ C, int ldc,
    const float* __restrict__ resid, int M, int K) {
    int m0 = blockIdx.y * 64;
    int n0 = blockIdx.x * 64;
    __shared__ u16 Ah[64][40];
    __shared__ u16 Al[64][40];
    __shared__ u16 Bh[64][40];
    __shared__ u16 Bl[64][40];
    int tid = threadIdx.x, lane = tid & 63, wid = tid >> 6;
    int wm = (wid >> 1) * 32, wn = (wid & 1) * 32;
    f32x4 acc[2][2] = {};
    for (int k0 = 0; k0 < K; k0 += 32) {
        {
            int r = tid >> 2, c = (tid & 3) * 8;
            const float* ap = A + (size_t)(m0 + r) * lda + k0 + c;
            f32x4 v0 = *(const f32x4*)ap;
            f32x4 v1 = *(const f32x4*)(ap + 4);
#pragma unroll
            for (int i = 0; i < 4; ++i) {
                u16 h, l;
                split1(v0[i], h, l); Ah[r][c + i] = h; Al[r][c + i] = l;
                split1(v1[i], h, l); Ah[r][c + 4 + i] = h; Al[r][c + 4 + i] = l;
            }
        }
        {
            int n = tid & 63, kb = tid >> 6;
#pragma unroll
            for (int i = 0; i < 8; ++i) {
                int kk = kb + i * 4;
                u16 h, l;
                split1(B[(size_t)(k0 + kk) * ldb + n0 + n], h, l);
                Bh[n][kk] = h; Bl[n][kk] = l;
            }
        }
        __syncthreads();
        bf16x8 ah[2], al[2], bh[2], bl[2];
#pragma unroll
        for (int mi = 0; mi < 2; ++mi) {
            ah[mi] = *(const bf16x8*)&Ah[wm + mi * 16 + (lane & 15)][(lane >> 4) * 8];
            al[mi] = *(const bf16x8*)&Al[wm + mi * 16 + (lane & 15)][(lane >> 4) * 8];
        }
#pragma unroll
        for (int ni = 0; ni < 2; ++ni) {
            bh[ni] = *(const bf16x8*)&Bh[wn + ni * 16 + (lane & 15)][(lane >> 4) * 8];
            bl[ni] = *(const bf16x8*)&Bl[wn + ni * 16 + (lane & 15)][(lane >> 4) * 8];
        }
#pragma unroll
        for (int mi = 0; mi < 2; ++mi)
#pragma unroll
            for (int ni = 0; ni < 2; ++ni) {
                acc[mi][ni] = __builtin_amdgcn_mfma_f32_16x16x32_bf16(ah[mi], bh[ni], acc[mi][ni], 0, 0, 0);
                acc[mi][ni] = __builtin_amdgcn_mfma_f32_16x16x32_bf16(ah[mi], bl[ni], acc[mi][ni], 0, 0, 0);
                acc[mi][ni] = __builtin_amdgcn_mfma_f32_16x16x32_bf16(al[mi], bh[ni], acc[mi][ni], 0, 0, 0);
            }
        __syncthreads();
    }
#pragma unroll
    for (int mi = 0; mi < 2; ++mi)
#pragma unroll
        for (int ni = 0; ni < 2; ++ni)
#pragma unroll
            for (int r = 0; r < 4; ++r) {
                int row = m0 + wm + mi * 16 + (lane >> 4) * 4 + r;
                int col = n0 + wn + ni * 16 + (lane & 15);
                float v = acc[mi][ni][r];
                if constexpr (EPI == 1) v += resid[(size_t)row * ldc + col];
                C[(size_t)row * ldc + col] = v;
            }
}

// ---------------- 1-term bf16 GEMM (MLP path): A bf16, B f32->bf16(hi), opt swiglu ----------------
template <int TM, bool SWIGLU>
__global__ __launch_bounds__(256) void k_gemm_bf(
    const u16* __restrict__ A, int lda, long sAe,
    const float* __restrict__ B, int ldb, long sBe,
    void* __restrict__ Cv, int ldc, long sCe,
    int M, int K, int pairOff,
    const int* __restrict__ counts, const int* __restrict__ rowidx) {
    int e = blockIdx.z;
    if (counts) M = counts[e];
    int m0 = blockIdx.y * TM;
    if (m0 >= M) return;
    A += (size_t)e * sAe;
    B += (size_t)e * sBe;
    int n0 = blockIdx.x * 64;

    __shared__ u16 As[TM][40];
    __shared__ u16 Bs[64][40];
    __shared__ u16 B2s[SWIGLU ? 64 : 1][40];

    int tid = threadIdx.x, lane = tid & 63, wid = tid >> 6;
    constexpr int MF = TM / 32;
    constexpr int NRR = (TM + 63) / 64;
    int wm = (wid >> 1) * (TM / 2), wn = (wid & 1) * 32;

    f32x4 acc[MF][2] = {};
    f32x4 acc2[SWIGLU ? MF : 1][2] = {};

    // hoist A row sources
    long asrc[NRR];
#pragma unroll
    for (int rr = 0; rr < NRR; ++rr) {
        int r = rr * 64 + (tid >> 2);
        int gm = m0 + r;
        if (r < TM && gm < M)
            asrc[rr] = rowidx ? (long)rowidx[e * CAP + gm] : (long)gm;
        else
            asrc[rr] = -1;
    }
    int cA = (tid & 3) * 8;

    for (int k0 = 0; k0 < K; k0 += 32) {
#pragma unroll
        for (int rr = 0; rr < NRR; ++rr) {
            int r = rr * 64 + (tid >> 2);
            if (r < TM) {
                bf16x8 v = {};
                if (asrc[rr] >= 0) v = *(const bf16x8*)(A + asrc[rr] * lda + k0 + cA);
                *(bf16x8*)&As[r][cA] = v;
            }
        }
        {
            int n = tid & 63, kb = tid >> 6;
#pragma unroll
            for (int i = 0; i < 8; ++i) {
                int kk = kb + i * 4;
                Bs[n][kk] = f2bf(B[(size_t)(k0 + kk) * ldb + n0 + n]);
                if constexpr (SWIGLU)
                    B2s[n][kk] = f2bf(B[(size_t)(k0 + kk) * ldb + n0 + pairOff + n]);
            }
        }
        __syncthreads();
        bf16x8 af[MF], bf[2], gf[SWIGLU ? 2 : 1];
#pragma unroll
        for (int mi = 0; mi < MF; ++mi)
            af[mi] = *(const bf16x8*)&As[wm + mi * 16 + (lane & 15)][(lane >> 4) * 8];
#pragma unroll
        for (int ni = 0; ni < 2; ++ni) {
            bf[ni] = *(const bf16x8*)&Bs[wn + ni * 16 + (lane & 15)][(lane >> 4) * 8];
            if constexpr (SWIGLU) gf[ni] = *(const bf16x8*)&B2s[wn + ni * 16 + (lane & 15)][(lane >> 4) * 8];
        }
#pragma unroll
        for (int mi = 0; mi < MF; ++mi)
#pragma unroll
            for (int ni = 0; ni < 2; ++ni) {
                acc[mi][ni] = __builtin_amdgcn_mfma_f32_16x16x32_bf16(af[mi], bf[ni], acc[mi][ni], 0, 0, 0);
                if constexpr (SWIGLU)
                    acc2[mi][ni] = __builtin_amdgcn_mfma_f32_16x16x32_bf16(af[mi], gf[ni], acc2[mi][ni], 0, 0, 0);
            }
        __syncthreads();
    }
#pragma unroll
    for (int mi = 0; mi < MF; ++mi)
#pragma unroll
        for (int ni = 0; ni < 2; ++ni)
#pragma unroll
            for (int r = 0; r < 4; ++r) {
                int row = m0 + wm + mi * 16 + (lane >> 4) * 4 + r;
                int col = n0 + wn + ni * 16 + (lane & 15);
                if (row >= M) continue;
                if constexpr (SWIGLU) {
                    float x1 = acc[mi][ni][r];
                    float x2 = acc2[mi][ni][r];
                    float val = x1 * (x2 / (1.f + __expf(-x2)));
                    ((u16*)Cv)[(size_t)e * sCe + (size_t)row * ldc + col] = f2bf(val);
                } else {
                    ((float*)Cv)[(size_t)e * sCe + (size_t)row * ldc + col] = acc[mi][ni][r];
                }
            }
}

// ---------------- unpack QKV + RoPE + q/k RMS norm -> pre-split bf16 hi/lo ----------------
__global__ __launch_bounds__(256) void k_rope(const float* __restrict__ qkv,
                                              const float* __restrict__ cosb,
                                              const float* __restrict__ sinb,
                                              const float* __restrict__ qn_w,
                                              const float* __restrict__ kn_w,
                                              u16* __restrict__ qh, u16* __restrict__ ql,
                                              u16* __restrict__ kh, u16* __restrict__ kl,
                                              u16* __restrict__ vh, u16* __restrict__ vl) {
    int wid = threadIdx.x >> 6, lane = threadIdx.x & 63;
    int idx = blockIdx.x * 4 + wid;   // 0..8191
    int s = idx >> 3, j = idx & 7;
    const float* base = qkv + (size_t)s * 2048 + j * 256;
    float c = cosb[s * HD + lane], sn = sinb[s * HD + lane];
    u16 hh, ll;
    split1(base[192 + lane], hh, ll);
    vh[((size_t)j * S + s) * HD + lane] = hh;
    vl[((size_t)j * S + s) * HD + lane] = ll;
#pragma unroll
    for (int r = 0; r < 3; ++r) {
        float x = base[r * 64 + lane];
        float xp = __shfl_xor(x, 32);
        float rot = (lane < 32) ? -xp : xp;
        float y = x * c + rot * sn;
        float ss = y * y;
#pragma unroll
        for (int o = 32; o; o >>= 1) ss += __shfl_xor(ss, o);
        float scale = rsqrtf(ss * (1.f / 64.f) + 1e-6f);
        float outv = y * scale * ((r == 2) ? kn_w[lane] : qn_w[lane]);
        split1(outv, hh, ll);
        if (r == 2) {
            kh[((size_t)j * S + s) * HD + lane] = hh;
            kl[((size_t)j * S + s) * HD + lane] = ll;
        } else {
            qh[((size_t)(j * 2 + r) * S + s) * HD + lane] = hh;
            ql[((size_t)(j * 2 + r) * S + s) * HD + lane] = ll;
        }
    }
}

// ---------------- scores = Q @ K^T * 0.125 (lower-triangle tiles), pre-split inputs ----------------
__global__ __launch_bounds__(256) void k_scores(const u16* __restrict__ qh, const u16* __restrict__ ql,
                                                const u16* __restrict__ kmh, const u16* __restrict__ kml,
                                                float* __restrict__ scores) {
    int kt = blockIdx.x, qt = blockIdx.y, h = blockIdx.z;
    if (kt > qt) return;
    size_t qoff = (size_t)h * S * HD;
    size_t koff = (size_t)(h >> 1) * S * HD;
    int lane = threadIdx.x & 63, wid = threadIdx.x >> 6;
    int wq = (wid >> 1) * 32, wk = (wid & 1) * 32;
    int q0 = qt * 64, k0 = kt * 64;
    f32x4 acc[2][2] = {};
#pragma unroll
    for (int ks = 0; ks < 2; ++ks) {
        bf16x8 ah[2], al[2], bh[2], bl[2];
#pragma unroll
        for (int mi = 0; mi < 2; ++mi) {
            size_t o = qoff + (size_t)(q0 + wq + mi * 16 + (lane & 15)) * HD + ks * 32 + (lane >> 4) * 8;
            ah[mi] = *(const bf16x8*)(qh + o);
            al[mi] = *(const bf16x8*)(ql + o);
        }
#pragma unroll
        for (int ni = 0; ni < 2; ++ni) {
            size_t o = koff + (size_t)(k0 + wk + ni * 16 + (lane & 15)) * HD + ks * 32 + (lane >> 4) * 8;
            bh[ni] = *(const bf16x8*)(kmh + o);
            bl[ni] = *(const bf16x8*)(kml + o);
        }
#pragma unroll
        for (int mi = 0; mi < 2; ++mi)
#pragma unroll
            for (int ni = 0; ni < 2; ++ni) {
                acc[mi][ni] = __builtin_amdgcn_mfma_f32_16x16x32_bf16(ah[mi], bh[ni], acc[mi][ni], 0, 0, 0);
                acc[mi][ni] = __builtin_amdgcn_mfma_f32_16x16x32_bf16(ah[mi], bl[ni], acc[mi][ni], 0, 0, 0);
                acc[mi][ni] = __builtin_amdgcn_mfma_f32_16x16x32_bf16(al[mi], bh[ni], acc[mi][ni], 0, 0, 0);
            }
    }
#pragma unroll
    for (int mi = 0; mi < 2; ++mi)
#pragma unroll
        for (int ni = 0; ni < 2; ++ni)
#pragma unroll
            for (int r = 0; r < 4; ++r) {
                int row = q0 + wq + mi * 16 + (lane >> 4) * 4 + r;
                int col = k0 + wk + ni * 16 + (lane & 15);
                scores[(size_t)h * S * S + (size_t)row * S + col] = acc[mi][ni][r] * 0.125f;
            }
}

// ---------------- causal softmax f32 -> P bf16 hi/lo ----------------
__global__ __launch_bounds__(256) void k_softmax(const float* __restrict__ scores,
                                                 u16* __restrict__ Ph, u16* __restrict__ Pl) {
    int wid = threadIdx.x >> 6, lane = threadIdx.x & 63;
    int q = blockIdx.x * 4 + wid, h = blockIdx.y;
    const float* row = scores + (size_t)h * S * S + (size_t)q * S;
    size_t po = (size_t)h * S * S + (size_t)q * S;
    int L = q + 1;
    float v[16];
    float mx = -1e30f;
#pragma unroll
    for (int i = 0; i < 16; ++i) {
        int idx = lane + i * 64;
        v[i] = (idx < L) ? row[idx] : -1e30f;
        mx = fmaxf(mx, v[i]);
    }
#pragma unroll
    for (int o = 32; o; o >>= 1) mx = fmaxf(mx, __shfl_xor(mx, o));
    float sum = 0.f;
#pragma unroll
    for (int i = 0; i < 16; ++i) {
        int idx = lane + i * 64;
        v[i] = (idx < L) ? __expf(v[i] - mx) : 0.f;
        sum += v[i];
    }
#pragma unroll
    for (int o = 32; o; o >>= 1) sum += __shfl_xor(sum, o);
    float inv = 1.f / sum;
#pragma unroll
    for (int i = 0; i < 16; ++i) {
        u16 hh, ll;
        split1(v[i] * inv, hh, ll);
        Ph[po + lane + i * 64] = hh;
        Pl[po + lane + i * 64] = ll;
    }
}

// ---------------- O = P @ V (pre-split), writes ao f32 in (s, h*64+d) layout ----------------
__global__ __launch_bounds__(256) void k_pv(const u16* __restrict__ Ph, const u16* __restrict__ Pl,
                                            const u16* __restrict__ vmh, const u16* __restrict__ vml,
                                            float* __restrict__ ao) {
    int qt = blockIdx.x, h = blockIdx.y;
    size_t poff = (size_t)h * S * S;
    size_t voff = (size_t)(h >> 1) * S * HD;
    __shared__ u16 Vh[64][72];
    __shared__ u16 Vl[64][72];
    int tid = threadIdx.x, lane = tid & 63, wid = tid >> 6;
    int wq = (wid >> 1) * 32, wd = (wid & 1) * 32;
    int q0 = qt * 64;
    f32x4 acc[2][2] = {};
    int kmax = (qt + 1) * 64;
    for (int kc = 0; kc < kmax; kc += 64) {
#pragma unroll
        for (int i = 0; i < 16; ++i) {
            int idx = tid + i * 256;
            int kr = idx >> 6, d = idx & 63;
            Vh[d][kr] = vmh[voff + (size_t)(kc + kr) * HD + d];
            Vl[d][kr] = vml[voff + (size_t)(kc + kr) * HD + d];
        }
        __syncthreads();
#pragma unroll
        for (int ks = 0; ks < 2; ++ks) {
            bf16x8 ph[2], pl[2], vh[2], vl[2];
#pragma unroll
            for (int mi = 0; mi < 2; ++mi) {
                size_t o = poff + (size_t)(q0 + wq + mi * 16 + (lane & 15)) * S + kc + ks * 32 + (lane >> 4) * 8;
                ph[mi] = *(const bf16x8*)(Ph + o);
                pl[mi] = *(const bf16x8*)(Pl + o);
            }
#pragma unroll
            for (int ni = 0; ni < 2; ++ni) {
                vh[ni] = *(const bf16x8*)&Vh[wd + ni * 16 + (lane & 15)][ks * 32 + (lane >> 4) * 8];
                vl[ni] = *(const bf16x8*)&Vl[wd + ni * 16 + (lane & 15)][ks * 32 + (lane >> 4) * 8];
            }
#pragma unroll
            for (int mi = 0; mi < 2; ++mi)
#pragma unroll
                for (int ni = 0; ni < 2; ++ni) {
                    acc[mi][ni] = __builtin_amdgcn_mfma_f32_16x16x32_bf16(ph[mi], vh[ni], acc[mi][ni], 0, 0, 0);
                    acc[mi][ni] = __builtin_amdgcn_mfma_f32_16x16x32_bf16(ph[mi], vl[ni], acc[mi][ni], 0, 0, 0);
                    acc[mi][ni] = __builtin_amdgcn_mfma_f32_16x16x32_bf16(pl[mi], vh[ni], acc[mi][ni], 0, 0, 0);
                }
        }
        __syncthreads();
    }
#pragma unroll
    for (int mi = 0; mi < 2; ++mi)
#pragma unroll
        for (int ni = 0; ni < 2; ++ni)
#pragma unroll
            for (int r = 0; r < 4; ++r) {
                int row = q0 + wq + mi * 16 + (lane >> 4) * 4 + r;
                int col = wd + ni * 16 + (lane & 15);
                ao[(size_t)row * MDIM + h * HD + col] = acc[mi][ni][r];
            }
}

// ---------------- router logits (f32): logits = h2 @ gate_w ----------------
__global__ __launch_bounds__(256) void k_logits(const float* __restrict__ h2,
                                                const float* __restrict__ gw,
                                                float* __restrict__ logits) {
    __shared__ float xr[1024];
    __shared__ float part[4][64];
    int s = blockIdx.x;
#pragma unroll
    for (int i = 0; i < 4; ++i) xr[threadIdx.x + i * 256] = h2[(size_t)s * MDIM + threadIdx.x + i * 256];
    __syncthreads();
    int e = threadIdx.x & 63, qq = threadIdx.x >> 6;
    float acc = 0.f;
    for (int i = 0; i < 256; ++i) acc += xr[qq * 256 + i] * gw[(size_t)(qq * 256 + i) * NE + e];
    part[qq][e] = acc;
    __syncthreads();
    if (threadIdx.x < 64)
        logits[(size_t)s * NE + threadIdx.x] =
            part[0][threadIdx.x] + part[1][threadIdx.x] + part[2][threadIdx.x] + part[3][threadIdx.x];
}

// ---------------- softmax + top-8 (tie -> lowest index) ----------------
__global__ __launch_bounds__(256) void k_topk(const float* __restrict__ logits,
                                              int* __restrict__ topi,
                                              float* __restrict__ wts) {
    int wid = threadIdx.x >> 6, lane = threadIdx.x & 63;
    int s = blockIdx.x * 4 + wid;
    float lg = logits[(size_t)s * NE + lane];
    float mx = lg;
#pragma unroll
    for (int o = 32; o; o >>= 1) mx = fmaxf(mx, __shfl_xor(mx, o));
    float ex = __expf(lg - mx);
    float sum = ex;
#pragma unroll
    for (int o = 32; o; o >>= 1) sum += __shfl_xor(sum, o);
    float g = ex / sum;
    float cur = g;
    float tv[TOPK]; int ti[TOPK];
    float tsum = 0.f;
#pragma unroll
    for (int k = 0; k < TOPK; ++k) {
        float v = cur; int ii = lane;
#pragma unroll
        for (int o = 32; o; o >>= 1) {
            float vo = __shfl_xor(v, o);
            int io = __shfl_xor(ii, o);
            if (vo > v || (vo == v && io < ii)) { v = vo; ii = io; }
        }
        tv[k] = v; ti[k] = ii; tsum += v;
        if (lane == ii) cur = -1.f;
    }
    float gs = fmaxf(tsum, 1.1920929e-07f);
    if (lane == 0) {
#pragma unroll
        for (int k = 0; k < TOPK; ++k) {
            topi[s * TOPK + k] = ti[k];
            wts[s * TOPK + k] = tv[k] / gs;
        }
    }
}

// ---------------- parallel rank-major priority / capacity assignment ----------------
__global__ __launch_bounds__(512) void k_slots(const int* __restrict__ topi, int* __restrict__ slots,
                                               int* __restrict__ counts, int* __restrict__ etok) {
    __shared__ int tl[S * TOPK];
    __shared__ int cnt[TOPK][NE];
    __shared__ int base[TOPK][NE];
    int tid = threadIdx.x;
    for (int i = tid; i < S * TOPK; i += 512) tl[i] = topi[i];
    ((int*)cnt)[tid] = 0;   // 512 == TOPK*NE
    __syncthreads();
    for (int i = tid; i < S * TOPK; i += 512)
        atomicAdd(&cnt[i & 7][tl[i]], 1);
    __syncthreads();
    if (tid < NE) {
        int acc = 0;
#pragma unroll
        for (int k = 0; k < TOPK; ++k) { base[k][tid] = acc; acc += cnt[k][tid]; }
        counts[tid] = acc < CAP ? acc : CAP;
    }
    __syncthreads();
    int k = tid >> 6, e = tid & 63;
    int rank = base[k][e];
    for (int s = 0; s < S; ++s) {
        if (tl[s * TOPK + k] == e) {
            if (rank < CAP) { slots[s * TOPK + k] = rank; etok[e * CAP + rank] = s; }
            else slots[s * TOPK + k] = -1;
            rank++;
        }
    }
}

// ---------------- final combine: out = h + shared + sum_k w_k * eo[e_k, slot_k] ----------------
__global__ __launch_bounds__(256) void k_combine(const float* __restrict__ h,
                                                 const float* __restrict__ sh,
                                                 const float* __restrict__ eo,
                                                 const int* __restrict__ topi,
                                                 const int* __restrict__ slots,
                                                 const float* __restrict__ wts,
                                                 float* __restrict__ out) {
    int s = blockIdx.x, t = threadIdx.x;
    float w[TOPK]; int off[TOPK];
#pragma unroll
    for (int k = 0; k < TOPK; ++k) {
        int sl = slots[s * TOPK + k];
        int ee = topi[s * TOPK + k];
        w[k] = wts[s * TOPK + k];
        off[k] = (sl >= 0) ? ee * CAP + sl : -1;
    }
#pragma unroll
    for (int i = 0; i < 4; ++i) {
        int col = t + i * 256;
        float acc = h[(size_t)s * MDIM + col] + sh[(size_t)s * MDIM + col];
#pragma unroll
        for (int k = 0; k < TOPK; ++k)
            if (off[k] >= 0) acc += w[k] * eo[(size_t)off[k] * MDIM + col];
        out[(size_t)s * MDIM + col] = acc;
    }
}

extern "C" void kernel_launch(void* const* d_in, const int* in_sizes, int n_in,
                              void* d_out, int out_size, void* d_ws, size_t ws_size,
                              hipStream_t stream) {
    (void)in_sizes; (void)n_in; (void)out_size; (void)ws_size;
    const float* hidden = (const float*)d_in[0];
    const float* cosb   = (const float*)d_in[1];
    const float* sinb   = (const float*)d_in[2];
    const float* ln1_w  = (const float*)d_in[3];
    const float* ln2_w  = (const float*)d_in[4];
    const float* qkv_w  = (const float*)d_in[5];
    const float* o_w    = (const float*)d_in[6];
    const float* qn_w   = (const float*)d_in[7];
    const float* kn_w   = (const float*)d_in[8];
    const float* sgu_w  = (const float*)d_in[9];
    const float* sdn_w  = (const float*)d_in[10];
    const float* gate_w = (const float*)d_in[11];
    const float* egu_w  = (const float*)d_in[12];
    const float* edn_w  = (const float*)d_in[13];
    float* out = (float*)d_out;

    char* ws = (char*)d_ws;
    size_t off = 0;
    auto alloc = [&](size_t bytes) -> void* {
        void* p = ws + off;
        off = (off + bytes + 255) & ~(size_t)255;
        return p;
    };
    float* hnf     = (float*)alloc((size_t)S * MDIM * 4);
    float* qkvb    = (float*)alloc((size_t)S * 2048 * 4);
    u16*   qhb     = (u16*)  alloc((size_t)NH * S * HD * 2);
    u16*   qlb     = (u16*)  alloc((size_t)NH * S * HD * 2);
    u16*   khb     = (u16*)  alloc((size_t)NKV * S * HD * 2);
    u16*   klb     = (u16*)  alloc((size_t)NKV * S * HD * 2);
    u16*   vhb     = (u16*)  alloc((size_t)NKV * S * HD * 2);
    u16*   vlb     = (u16*)  alloc((size_t)NKV * S * HD * 2);
    float* scores  = (float*)alloc((size_t)NH * S * S * 4);
    u16*   Phb     = (u16*)  alloc((size_t)NH * S * S * 2);
    u16*   Plb     = (u16*)  alloc((size_t)NH * S * S * 2);
    float* aof     = (float*)alloc((size_t)S * MDIM * 4);
    float* hbuf    = (float*)alloc((size_t)S * MDIM * 4);
    float* h2f     = (float*)alloc((size_t)S * MDIM * 4);
    u16*   h2b     = (u16*)  alloc((size_t)S * MDIM * 2);
    u16*   gatedS  = (u16*)  alloc((size_t)S * FF * 2);
    float* sharedO = (float*)alloc((size_t)S * MDIM * 4);
    float* logits  = (float*)alloc((size_t)S * NE * 4);
    int*   topi    = (int*)  alloc((size_t)S * TOPK * 4);
    float* wts     = (float*)alloc((size_t)S * TOPK * 4);
    int*   slots   = (int*)  alloc((size_t)S * TOPK * 4);
    int*   counts  = (int*)  alloc((size_t)NE * 4);
    int*   etok    = (int*)  alloc((size_t)NE * CAP * 4);
    u16*   egated  = (u16*)  alloc((size_t)NE * CAP * FF * 2);
    float* eo      = (float*)alloc((size_t)NE * CAP * MDIM * 4);

    // 1. RMS norm 1 -> hn (f32)
    k_rms<<<dim3(S), 256, 0, stream>>>(hidden, ln1_w, hnf, nullptr);
    // 2. QKV projection (3-term split)
    k_gemm_split<0><<<dim3(2048 / 64, S / 64), 256, 0, stream>>>(
        hnf, MDIM, qkv_w, 2048, qkvb, 2048, nullptr, S, MDIM);
    // 3. unpack + RoPE + q/k RMS -> pre-split bf16
    k_rope<<<dim3(S * NKV / 4), 256, 0, stream>>>(qkvb, cosb, sinb, qn_w, kn_w,
                                                  qhb, qlb, khb, klb, vhb, vlb);
    // 4. scores (lower triangle, 3-term)
    k_scores<<<dim3(16, 16, NH), 256, 0, stream>>>(qhb, qlb, khb, klb, scores);
    // 5. causal softmax -> P hi/lo
    k_softmax<<<dim3(S / 4, NH), 256, 0, stream>>>(scores, Phb, Plb);
    // 6. P @ V -> ao f32 (3-term)
    k_pv<<<dim3(16, NH), 256, 0, stream>>>(Phb, Plb, vhb, vlb, aof);
    // 7. O projection + residual -> h f32 (3-term)
    k_gemm_split<1><<<dim3(MDIM / 64, S / 64), 256, 0, stream>>>(
        aof, MDIM, o_w, MDIM, hbuf, MDIM, hidden, S, MDIM);
    // 8. RMS norm 2 -> h2 (f32 + bf16)
    k_rms<<<dim3(S), 256, 0, stream>>>(hbuf, ln2_w, h2f, h2b);
    // 9. router logits (f32)
    k_logits<<<dim3(S), 256, 0, stream>>>(h2f, gate_w, logits);
    // 10. softmax + top-8
    k_topk<<<dim3(S / 4), 256, 0, stream>>>(logits, topi, wts);
    // 11. capacity / slot assignment (parallel, exact reference semantics)
    k_slots<<<dim3(1), 512, 0, stream>>>(topi, slots, counts, etok);
    // 12. shared MLP up+gate (fused swiglu) -> gatedS bf16
    k_gemm_bf<128, true><<<dim3(FF / 64, S / 128), 256, 0, stream>>>(
        h2b, MDIM, 0, sgu_w, 2 * FF, 0, gatedS, FF, 0, S, MDIM, FF, nullptr, nullptr);
    // 13. shared MLP down -> sharedO f32
    k_gemm_bf<128, false><<<dim3(MDIM / 64, S / 128), 256, 0, stream>>>(
        gatedS, FF, 0, sdn_w, MDIM, 0, sharedO, MDIM, 0, S, FF, 0, nullptr, nullptr);
    // 14. expert up+gate (fused swiglu, gather-on-the-fly) -> egated bf16
    k_gemm_bf<160, true><<<dim3(FF / 64, (CAP + 159) / 160, NE), 256, 0, stream>>>(
        h2b, MDIM, 0, egu_w, 2 * FF, (long)MDIM * 2 * FF,
        egated, FF, (long)CAP * FF, CAP, MDIM, FF, counts, etok);
    // 15. expert down -> eo f32
    k_gemm_bf<160, false><<<dim3(MDIM / 64, (CAP + 159) / 160, NE), 256, 0, stream>>>(
        egated, FF, (long)CAP * FF, edn_w, MDIM, (long)FF * MDIM,
        eo, MDIM, (long)CAP * MDIM, CAP, FF, 0, counts, nullptr);
    // 16. combine: out = h + shared + moe
    k_combine<<<dim3(S), 256, 0, stream>>>(hbuf, sharedO, eo, topi, slots, wts, out);
}

// Round 4
// 1497.376 us; speedup vs baseline: 1.6784x; 1.0122x over previous
//
#include <hip/hip_runtime.h>

#define S 1024
#define MDIM 1024
#define NH 16
#define HD 64
#define NKV 8
#define FF 3072
#define NE 64
#define TOPK 8
#define CAP 256

typedef unsigned short u16;
typedef __attribute__((ext_vector_type(8))) short bf16x8;
typedef __attribute__((ext_vector_type(4))) float f32x4;

__device__ __forceinline__ u16 f2bf(float f) {
    union { float f; unsigned u; } x; x.f = f;
    unsigned r = x.u + 0x7FFFu + ((x.u >> 16) & 1u);
    return (u16)(r >> 16);
}
__device__ __forceinline__ float bf2f(u16 b) {
    union { unsigned u; float f; } x; x.u = ((unsigned)b) << 16;
    return x.f;
}
__device__ __forceinline__ void split1(float x, u16& h, u16& l) {
    h = f2bf(x);
    l = f2bf(x - bf2f(h));
}
// swizzled column (u16 units) for k-octet group G in row `row` of a [R][40] tile
__device__ __forceinline__ int swzcol(int row, int G) { return 8 * (G ^ ((row >> 3) & 3)); }

// ---------------- RMS norm (row of 1024), f32 out + optional bf16 out ----------------
__global__ __launch_bounds__(256) void k_rms(const float* __restrict__ x,
                                             const float* __restrict__ w,
                                             float* __restrict__ o,
                                             u16* __restrict__ obf) {
    int s = blockIdx.x;
    const float* row = x + (size_t)s * MDIM;
    float v[4]; float ss = 0.f;
#pragma unroll
    for (int i = 0; i < 4; ++i) { v[i] = row[threadIdx.x + i * 256]; ss += v[i] * v[i]; }
#pragma unroll
    for (int of = 32; of; of >>= 1) ss += __shfl_xor(ss, of);
    __shared__ float red[4];
    int wid = threadIdx.x >> 6;
    if ((threadIdx.x & 63) == 0) red[wid] = ss;
    __syncthreads();
    float tot = red[0] + red[1] + red[2] + red[3];
    float sc = rsqrtf(tot * (1.f / MDIM) + 1e-6f);
#pragma unroll
    for (int i = 0; i < 4; ++i) {
        int c = threadIdx.x + i * 256;
        float ov = v[i] * sc * w[c];
        o[(size_t)s * MDIM + c] = ov;
        if (obf) obf[(size_t)s * MDIM + c] = f2bf(ov);
    }
}

// ---------------- 3-term split GEMM (routing-critical path): C = A(f32)@B(f32) ----------------
// EPI: 0 = f32 out, 1 = f32 out + resid
template <int EPI>
__global__ __launch_bounds__(256) void k_gemm_split(
    const float* __restrict__ A, int lda,
    const float* __restrict__ B, int ldb,
    float* __restrict__ C, int ldc,
    const float* __restrict__ resid, int M, int K) {
    int m0 = blockIdx.y * 64;
    int n0 = blockIdx.x * 64;
    __shared__ u16 Ah[64][40];
    __shared__ u16 Al[64][40];
    __shared__ u16 Bh[64][40];
    __shared__ u16 Bl[64][40];
    int tid = threadIdx.x, lane = tid & 63, wid = tid >> 6;
    int wm = (wid >> 1) * 32, wn = (wid & 1) * 32;
    f32x4 acc[2][2] = {};
    int rA = tid >> 2, GA = tid & 3;          // A: row, k-octet
    int nB = tid & 63, kbB = tid >> 6;        // B: col, k-octet
    int colA = swzcol(rA, GA);
    int colB = swzcol(nB, kbB);
    for (int k0 = 0; k0 < K; k0 += 32) {
        {
            const float* ap = A + (size_t)(m0 + rA) * lda + k0 + GA * 8;
            f32x4 v0 = *(const f32x4*)ap;
            f32x4 v1 = *(const f32x4*)(ap + 4);
            bf16x8 hh, ll;
#pragma unroll
            for (int i = 0; i < 4; ++i) {
                u16 h, l;
                split1(v0[i], h, l); hh[i] = (short)h; ll[i] = (short)l;
                split1(v1[i], h, l); hh[i + 4] = (short)h; ll[i + 4] = (short)l;
            }
            *(bf16x8*)&Ah[rA][colA] = hh;
            *(bf16x8*)&Al[rA][colA] = ll;
        }
        {
            const float* bp = B + (size_t)(k0 + kbB * 8) * ldb + n0 + nB;
            bf16x8 hh, ll;
#pragma unroll
            for (int i = 0; i < 8; ++i) {
                u16 h, l;
                split1(bp[(size_t)i * ldb], h, l);
                hh[i] = (short)h; ll[i] = (short)l;
            }
            *(bf16x8*)&Bh[nB][colB] = hh;
            *(bf16x8*)&Bl[nB][colB] = ll;
        }
        __syncthreads();
        bf16x8 ah[2], al[2], bh[2], bl[2];
#pragma unroll
        for (int mi = 0; mi < 2; ++mi) {
            int r = wm + mi * 16 + (lane & 15);
            int c = swzcol(r, lane >> 4);
            ah[mi] = *(const bf16x8*)&Ah[r][c];
            al[mi] = *(const bf16x8*)&Al[r][c];
        }
#pragma unroll
        for (int ni = 0; ni < 2; ++ni) {
            int r = wn + ni * 16 + (lane & 15);
            int c = swzcol(r, lane >> 4);
            bh[ni] = *(const bf16x8*)&Bh[r][c];
            bl[ni] = *(const bf16x8*)&Bl[r][c];
        }
#pragma unroll
        for (int mi = 0; mi < 2; ++mi)
#pragma unroll
            for (int ni = 0; ni < 2; ++ni) {
                acc[mi][ni] = __builtin_amdgcn_mfma_f32_16x16x32_bf16(ah[mi], bh[ni], acc[mi][ni], 0, 0, 0);
                acc[mi][ni] = __builtin_amdgcn_mfma_f32_16x16x32_bf16(ah[mi], bl[ni], acc[mi][ni], 0, 0, 0);
                acc[mi][ni] = __builtin_amdgcn_mfma_f32_16x16x32_bf16(al[mi], bh[ni], acc[mi][ni], 0, 0, 0);
            }
        __syncthreads();
    }
#pragma unroll
    for (int mi = 0; mi < 2; ++mi)
#pragma unroll
        for (int ni = 0; ni < 2; ++ni)
#pragma unroll
            for (int r = 0; r < 4; ++r) {
                int row = m0 + wm + mi * 16 + (lane >> 4) * 4 + r;
                int col = n0 + wn + ni * 16 + (lane & 15);
                float v = acc[mi][ni][r];
                if constexpr (EPI == 1) v += resid[(size_t)row * ldc + col];
                C[(size_t)row * ldc + col] = v;
            }
}

// ---------------- 1-term bf16 GEMM (MLP path): A bf16, B f32->bf16(hi), opt swiglu ----------------
template <int TM, bool SWIGLU>
__global__ __launch_bounds__(256) void k_gemm_bf(
    const u16* __restrict__ A, int lda, long sAe,
    const float* __restrict__ B, int ldb, long sBe,
    void* __restrict__ Cv, int ldc, long sCe,
    int M, int K, int pairOff,
    const int* __restrict__ counts, const int* __restrict__ rowidx) {
    int e = blockIdx.z;
    if (counts) M = counts[e];
    int m0 = blockIdx.y * TM;
    if (m0 >= M) return;
    A += (size_t)e * sAe;
    B += (size_t)e * sBe;
    int n0 = blockIdx.x * 64;

    __shared__ u16 As[TM][40];
    __shared__ u16 Bs[64][40];
    __shared__ u16 B2s[SWIGLU ? 64 : 1][40];

    int tid = threadIdx.x, lane = tid & 63, wid = tid >> 6;
    constexpr int MF = TM / 32;
    constexpr int NRR = (TM + 63) / 64;
    int wm = (wid >> 1) * (TM / 2), wn = (wid & 1) * 32;

    f32x4 acc[MF][2] = {};
    f32x4 acc2[SWIGLU ? MF : 1][2] = {};

    // hoist A row sources
    long asrc[NRR];
#pragma unroll
    for (int rr = 0; rr < NRR; ++rr) {
        int r = rr * 64 + (tid >> 2);
        int gm = m0 + r;
        if (r < TM && gm < M)
            asrc[rr] = rowidx ? (long)rowidx[e * CAP + gm] : (long)gm;
        else
            asrc[rr] = -1;
    }
    int GA = tid & 3;
    int nB = tid & 63, kbB = tid >> 6;
    int colB = swzcol(nB, kbB);

    for (int k0 = 0; k0 < K; k0 += 32) {
#pragma unroll
        for (int rr = 0; rr < NRR; ++rr) {
            int r = rr * 64 + (tid >> 2);
            if (r < TM) {
                bf16x8 v = {};
                if (asrc[rr] >= 0) v = *(const bf16x8*)(A + asrc[rr] * lda + k0 + GA * 8);
                *(bf16x8*)&As[r][swzcol(r, GA)] = v;
            }
        }
        {
            const float* bp = B + (size_t)(k0 + kbB * 8) * ldb + n0 + nB;
            bf16x8 v;
#pragma unroll
            for (int i = 0; i < 8; ++i) v[i] = (short)f2bf(bp[(size_t)i * ldb]);
            *(bf16x8*)&Bs[nB][colB] = v;
            if constexpr (SWIGLU) {
                const float* gp = bp + pairOff;
                bf16x8 g;
#pragma unroll
                for (int i = 0; i < 8; ++i) g[i] = (short)f2bf(gp[(size_t)i * ldb]);
                *(bf16x8*)&B2s[nB][colB] = g;
            }
        }
        __syncthreads();
        bf16x8 af[MF], bf[2], gf[SWIGLU ? 2 : 1];
#pragma unroll
        for (int mi = 0; mi < MF; ++mi) {
            int r = wm + mi * 16 + (lane & 15);
            af[mi] = *(const bf16x8*)&As[r][swzcol(r, lane >> 4)];
        }
#pragma unroll
        for (int ni = 0; ni < 2; ++ni) {
            int r = wn + ni * 16 + (lane & 15);
            int c = swzcol(r, lane >> 4);
            bf[ni] = *(const bf16x8*)&Bs[r][c];
            if constexpr (SWIGLU) gf[ni] = *(const bf16x8*)&B2s[r][c];
        }
#pragma unroll
        for (int mi = 0; mi < MF; ++mi)
#pragma unroll
            for (int ni = 0; ni < 2; ++ni) {
                acc[mi][ni] = __builtin_amdgcn_mfma_f32_16x16x32_bf16(af[mi], bf[ni], acc[mi][ni], 0, 0, 0);
                if constexpr (SWIGLU)
                    acc2[mi][ni] = __builtin_amdgcn_mfma_f32_16x16x32_bf16(af[mi], gf[ni], acc2[mi][ni], 0, 0, 0);
            }
        __syncthreads();
    }
#pragma unroll
    for (int mi = 0; mi < MF; ++mi)
#pragma unroll
        for (int ni = 0; ni < 2; ++ni)
#pragma unroll
            for (int r = 0; r < 4; ++r) {
                int row = m0 + wm + mi * 16 + (lane >> 4) * 4 + r;
                int col = n0 + wn + ni * 16 + (lane & 15);
                if (row >= M) continue;
                if constexpr (SWIGLU) {
                    float x1 = acc[mi][ni][r];
                    float x2 = acc2[mi][ni][r];
                    float val = x1 * (x2 / (1.f + __expf(-x2)));
                    ((u16*)Cv)[(size_t)e * sCe + (size_t)row * ldc + col] = f2bf(val);
                } else {
                    ((float*)Cv)[(size_t)e * sCe + (size_t)row * ldc + col] = acc[mi][ni][r];
                }
            }
}

// ---------------- unpack QKV + RoPE + q/k RMS norm -> pre-split bf16 hi/lo ----------------
__global__ __launch_bounds__(256) void k_rope(const float* __restrict__ qkv,
                                              const float* __restrict__ cosb,
                                              const float* __restrict__ sinb,
                                              const float* __restrict__ qn_w,
                                              const float* __restrict__ kn_w,
                                              u16* __restrict__ qh, u16* __restrict__ ql,
                                              u16* __restrict__ kh, u16* __restrict__ kl,
                                              u16* __restrict__ vh, u16* __restrict__ vl) {
    int wid = threadIdx.x >> 6, lane = threadIdx.x & 63;
    int idx = blockIdx.x * 4 + wid;   // 0..8191
    int s = idx >> 3, j = idx & 7;
    const float* base = qkv + (size_t)s * 2048 + j * 256;
    float c = cosb[s * HD + lane], sn = sinb[s * HD + lane];
    u16 hh, ll;
    split1(base[192 + lane], hh, ll);
    vh[((size_t)j * S + s) * HD + lane] = hh;
    vl[((size_t)j * S + s) * HD + lane] = ll;
#pragma unroll
    for (int r = 0; r < 3; ++r) {
        float x = base[r * 64 + lane];
        float xp = __shfl_xor(x, 32);
        float rot = (lane < 32) ? -xp : xp;
        float y = x * c + rot * sn;
        float ss = y * y;
#pragma unroll
        for (int o = 32; o; o >>= 1) ss += __shfl_xor(ss, o);
        float scale = rsqrtf(ss * (1.f / 64.f) + 1e-6f);
        float outv = y * scale * ((r == 2) ? kn_w[lane] : qn_w[lane]);
        split1(outv, hh, ll);
        if (r == 2) {
            kh[((size_t)j * S + s) * HD + lane] = hh;
            kl[((size_t)j * S + s) * HD + lane] = ll;
        } else {
            qh[((size_t)(j * 2 + r) * S + s) * HD + lane] = hh;
            ql[((size_t)(j * 2 + r) * S + s) * HD + lane] = ll;
        }
    }
}

// ---------------- scores = Q @ K^T * 0.125 (lower-triangle tiles), pre-split inputs ----------------
__global__ __launch_bounds__(256) void k_scores(const u16* __restrict__ qh, const u16* __restrict__ ql,
                                                const u16* __restrict__ kmh, const u16* __restrict__ kml,
                                                float* __restrict__ scores) {
    int kt = blockIdx.x, qt = blockIdx.y, h = blockIdx.z;
    if (kt > qt) return;
    size_t qoff = (size_t)h * S * HD;
    size_t koff = (size_t)(h >> 1) * S * HD;
    int lane = threadIdx.x & 63, wid = threadIdx.x >> 6;
    int wq = (wid >> 1) * 32, wk = (wid & 1) * 32;
    int q0 = qt * 64, k0 = kt * 64;
    f32x4 acc[2][2] = {};
#pragma unroll
    for (int ks = 0; ks < 2; ++ks) {
        bf16x8 ah[2], al[2], bh[2], bl[2];
#pragma unroll
        for (int mi = 0; mi < 2; ++mi) {
            size_t o = qoff + (size_t)(q0 + wq + mi * 16 + (lane & 15)) * HD + ks * 32 + (lane >> 4) * 8;
            ah[mi] = *(const bf16x8*)(qh + o);
            al[mi] = *(const bf16x8*)(ql + o);
        }
#pragma unroll
        for (int ni = 0; ni < 2; ++ni) {
            size_t o = koff + (size_t)(k0 + wk + ni * 16 + (lane & 15)) * HD + ks * 32 + (lane >> 4) * 8;
            bh[ni] = *(const bf16x8*)(kmh + o);
            bl[ni] = *(const bf16x8*)(kml + o);
        }
#pragma unroll
        for (int mi = 0; mi < 2; ++mi)
#pragma unroll
            for (int ni = 0; ni < 2; ++ni) {
                acc[mi][ni] = __builtin_amdgcn_mfma_f32_16x16x32_bf16(ah[mi], bh[ni], acc[mi][ni], 0, 0, 0);
                acc[mi][ni] = __builtin_amdgcn_mfma_f32_16x16x32_bf16(ah[mi], bl[ni], acc[mi][ni], 0, 0, 0);
                acc[mi][ni] = __builtin_amdgcn_mfma_f32_16x16x32_bf16(al[mi], bh[ni], acc[mi][ni], 0, 0, 0);
            }
    }
#pragma unroll
    for (int mi = 0; mi < 2; ++mi)
#pragma unroll
        for (int ni = 0; ni < 2; ++ni)
#pragma unroll
            for (int r = 0; r < 4; ++r) {
                int row = q0 + wq + mi * 16 + (lane >> 4) * 4 + r;
                int col = k0 + wk + ni * 16 + (lane & 15);
                scores[(size_t)h * S * S + (size_t)row * S + col] = acc[mi][ni][r] * 0.125f;
            }
}

// ---------------- causal softmax f32 -> P bf16 hi/lo ----------------
__global__ __launch_bounds__(256) void k_softmax(const float* __restrict__ scores,
                                                 u16* __restrict__ Ph, u16* __restrict__ Pl) {
    int wid = threadIdx.x >> 6, lane = threadIdx.x & 63;
    int q = blockIdx.x * 4 + wid, h = blockIdx.y;
    const float* row = scores + (size_t)h * S * S + (size_t)q * S;
    size_t po = (size_t)h * S * S + (size_t)q * S;
    int L = q + 1;
    float v[16];
    float mx = -1e30f;
#pragma unroll
    for (int i = 0; i < 16; ++i) {
        int idx = lane + i * 64;
        v[i] = (idx < L) ? row[idx] : -1e30f;
        mx = fmaxf(mx, v[i]);
    }
#pragma unroll
    for (int o = 32; o; o >>= 1) mx = fmaxf(mx, __shfl_xor(mx, o));
    float sum = 0.f;
#pragma unroll
    for (int i = 0; i < 16; ++i) {
        int idx = lane + i * 64;
        v[i] = (idx < L) ? __expf(v[i] - mx) : 0.f;
        sum += v[i];
    }
#pragma unroll
    for (int o = 32; o; o >>= 1) sum += __shfl_xor(sum, o);
    float inv = 1.f / sum;
#pragma unroll
    for (int i = 0; i < 16; ++i) {
        u16 hh, ll;
        split1(v[i] * inv, hh, ll);
        Ph[po + lane + i * 64] = hh;
        Pl[po + lane + i * 64] = ll;
    }
}

// ---------------- O = P @ V (pre-split), writes ao f32 in (s, h*64+d) layout ----------------
__global__ __launch_bounds__(256) void k_pv(const u16* __restrict__ Ph, const u16* __restrict__ Pl,
                                            const u16* __restrict__ vmh, const u16* __restrict__ vml,
                                            float* __restrict__ ao) {
    int qt = blockIdx.x, h = blockIdx.y;
    size_t poff = (size_t)h * S * S;
    size_t voff = (size_t)(h >> 1) * S * HD;
    __shared__ u16 Vh[64][72];
    __shared__ u16 Vl[64][72];
    int tid = threadIdx.x, lane = tid & 63, wid = tid >> 6;
    int wq = (wid >> 1) * 32, wd = (wid & 1) * 32;
    int q0 = qt * 64;
    f32x4 acc[2][2] = {};
    int kmax = (qt + 1) * 64;
    for (int kc = 0; kc < kmax; kc += 64) {
#pragma unroll
        for (int i = 0; i < 16; ++i) {
            int idx = tid + i * 256;
            int kr = idx >> 6, d = idx & 63;
            Vh[d][kr] = vmh[voff + (size_t)(kc + kr) * HD + d];
            Vl[d][kr] = vml[voff + (size_t)(kc + kr) * HD + d];
        }
        __syncthreads();
#pragma unroll
        for (int ks = 0; ks < 2; ++ks) {
            bf16x8 ph[2], pl[2], vh[2], vl[2];
#pragma unroll
            for (int mi = 0; mi < 2; ++mi) {
                size_t o = poff + (size_t)(q0 + wq + mi * 16 + (lane & 15)) * S + kc + ks * 32 + (lane >> 4) * 8;
                ph[mi] = *(const bf16x8*)(Ph + o);
                pl[mi] = *(const bf16x8*)(Pl + o);
            }
#pragma unroll
            for (int ni = 0; ni < 2; ++ni) {
                vh[ni] = *(const bf16x8*)&Vh[wd + ni * 16 + (lane & 15)][ks * 32 + (lane >> 4) * 8];
                vl[ni] = *(const bf16x8*)&Vl[wd + ni * 16 + (lane & 15)][ks * 32 + (lane >> 4) * 8];
            }
#pragma unroll
            for (int mi = 0; mi < 2; ++mi)
#pragma unroll
                for (int ni = 0; ni < 2; ++ni) {
                    acc[mi][ni] = __builtin_amdgcn_mfma_f32_16x16x32_bf16(ph[mi], vh[ni], acc[mi][ni], 0, 0, 0);
                    acc[mi][ni] = __builtin_amdgcn_mfma_f32_16x16x32_bf16(ph[mi], vl[ni], acc[mi][ni], 0, 0, 0);
                    acc[mi][ni] = __builtin_amdgcn_mfma_f32_16x16x32_bf16(pl[mi], vh[ni], acc[mi][ni], 0, 0, 0);
                }
        }
        __syncthreads();
    }
#pragma unroll
    for (int mi = 0; mi < 2; ++mi)
#pragma unroll
        for (int ni = 0; ni < 2; ++ni)
#pragma unroll
            for (int r = 0; r < 4; ++r) {
                int row = q0 + wq + mi * 16 + (lane >> 4) * 4 + r;
                int col = wd + ni * 16 + (lane & 15);
                ao[(size_t)row * MDIM + h * HD + col] = acc[mi][ni][r];
            }
}

// ---------------- router logits (f32): logits = h2 @ gate_w ----------------
__global__ __launch_bounds__(256) void k_logits(const float* __restrict__ h2,
                                                const float* __restrict__ gw,
                                                float* __restrict__ logits) {
    __shared__ float xr[1024];
    __shared__ float part[4][64];
    int s = blockIdx.x;
#pragma unroll
    for (int i = 0; i < 4; ++i) xr[threadIdx.x + i * 256] = h2[(size_t)s * MDIM + threadIdx.x + i * 256];
    __syncthreads();
    int e = threadIdx.x & 63, qq = threadIdx.x >> 6;
    float acc = 0.f;
    for (int i = 0; i < 256; ++i) acc += xr[qq * 256 + i] * gw[(size_t)(qq * 256 + i) * NE + e];
    part[qq][e] = acc;
    __syncthreads();
    if (threadIdx.x < 64)
        logits[(size_t)s * NE + threadIdx.x] =
            part[0][threadIdx.x] + part[1][threadIdx.x] + part[2][threadIdx.x] + part[3][threadIdx.x];
}

// ---------------- softmax + top-8 (tie -> lowest index) ----------------
__global__ __launch_bounds__(256) void k_topk(const float* __restrict__ logits,
                                              int* __restrict__ topi,
                                              float* __restrict__ wts) {
    int wid = threadIdx.x >> 6, lane = threadIdx.x & 63;
    int s = blockIdx.x * 4 + wid;
    float lg = logits[(size_t)s * NE + lane];
    float mx = lg;
#pragma unroll
    for (int o = 32; o; o >>= 1) mx = fmaxf(mx, __shfl_xor(mx, o));
    float ex = __expf(lg - mx);
    float sum = ex;
#pragma unroll
    for (int o = 32; o; o >>= 1) sum += __shfl_xor(sum, o);
    float g = ex / sum;
    float cur = g;
    float tv[TOPK]; int ti[TOPK];
    float tsum = 0.f;
#pragma unroll
    for (int k = 0; k < TOPK; ++k) {
        float v = cur; int ii = lane;
#pragma unroll
        for (int o = 32; o; o >>= 1) {
            float vo = __shfl_xor(v, o);
            int io = __shfl_xor(ii, o);
            if (vo > v || (vo == v && io < ii)) { v = vo; ii = io; }
        }
        tv[k] = v; ti[k] = ii; tsum += v;
        if (lane == ii) cur = -1.f;
    }
    float gs = fmaxf(tsum, 1.1920929e-07f);
    if (lane == 0) {
#pragma unroll
        for (int k = 0; k < TOPK; ++k) {
            topi[s * TOPK + k] = ti[k];
            wts[s * TOPK + k] = tv[k] / gs;
        }
    }
}

// ---------------- parallel rank-major priority / capacity assignment ----------------
__global__ __launch_bounds__(512) void k_slots(const int* __restrict__ topi, int* __restrict__ slots,
                                               int* __restrict__ counts, int* __restrict__ etok) {
    __shared__ int tl[S * TOPK];
    __shared__ int cnt[TOPK][NE];
    __shared__ int base[TOPK][NE];
    int tid = threadIdx.x;
    for (int i = tid; i < S * TOPK; i += 512) tl[i] = topi[i];
    ((int*)cnt)[tid] = 0;   // 512 == TOPK*NE
    __syncthreads();
    for (int i = tid; i < S * TOPK; i += 512)
        atomicAdd(&cnt[i & 7][tl[i]], 1);
    __syncthreads();
    if (tid < NE) {
        int acc = 0;
#pragma unroll
        for (int k = 0; k < TOPK; ++k) { base[k][tid] = acc; acc += cnt[k][tid]; }
        counts[tid] = acc < CAP ? acc : CAP;
    }
    __syncthreads();
    int k = tid >> 6, e = tid & 63;
    int rank = base[k][e];
    for (int s = 0; s < S; ++s) {
        if (tl[s * TOPK + k] == e) {
            if (rank < CAP) { slots[s * TOPK + k] = rank; etok[e * CAP + rank] = s; }
            else slots[s * TOPK + k] = -1;
            rank++;
        }
    }
}

// ---------------- final combine: out = h + shared + sum_k w_k * eo[e_k, slot_k] ----------------
__global__ __launch_bounds__(256) void k_combine(const float* __restrict__ h,
                                                 const float* __restrict__ sh,
                                                 const float* __restrict__ eo,
                                                 const int* __restrict__ topi,
                                                 const int* __restrict__ slots,
                                                 const float* __restrict__ wts,
                                                 float* __restrict__ out) {
    int s = blockIdx.x, t = threadIdx.x;
    float w[TOPK]; int off[TOPK];
#pragma unroll
    for (int k = 0; k < TOPK; ++k) {
        int sl = slots[s * TOPK + k];
        int ee = topi[s * TOPK + k];
        w[k] = wts[s * TOPK + k];
        off[k] = (sl >= 0) ? ee * CAP + sl : -1;
    }
#pragma unroll
    for (int i = 0; i < 4; ++i) {
        int col = t + i * 256;
        float acc = h[(size_t)s * MDIM + col] + sh[(size_t)s * MDIM + col];
#pragma unroll
        for (int k = 0; k < TOPK; ++k)
            if (off[k] >= 0) acc += w[k] * eo[(size_t)off[k] * MDIM + col];
        out[(size_t)s * MDIM + col] = acc;
    }
}

extern "C" void kernel_launch(void* const* d_in, const int* in_sizes, int n_in,
                              void* d_out, int out_size, void* d_ws, size_t ws_size,
                              hipStream_t stream) {
    (void)in_sizes; (void)n_in; (void)out_size; (void)ws_size;
    const float* hidden = (const float*)d_in[0];
    const float* cosb   = (const float*)d_in[1];
    const float* sinb   = (const float*)d_in[2];
    const float* ln1_w  = (const float*)d_in[3];
    const float* ln2_w  = (const float*)d_in[4];
    const float* qkv_w  = (const float*)d_in[5];
    const float* o_w    = (const float*)d_in[6];
    const float* qn_w   = (const float*)d_in[7];
    const float* kn_w   = (const float*)d_in[8];
    const float* sgu_w  = (const float*)d_in[9];
    const float* sdn_w  = (const float*)d_in[10];
    const float* gate_w = (const float*)d_in[11];
    const float* egu_w  = (const float*)d_in[12];
    const float* edn_w  = (const float*)d_in[13];
    float* out = (float*)d_out;

    char* ws = (char*)d_ws;
    size_t off = 0;
    auto alloc = [&](size_t bytes) -> void* {
        void* p = ws + off;
        off = (off + bytes + 255) & ~(size_t)255;
        return p;
    };
    float* hnf     = (float*)alloc((size_t)S * MDIM * 4);
    float* qkvb    = (float*)alloc((size_t)S * 2048 * 4);
    u16*   qhb     = (u16*)  alloc((size_t)NH * S * HD * 2);
    u16*   qlb     = (u16*)  alloc((size_t)NH * S * HD * 2);
    u16*   khb     = (u16*)  alloc((size_t)NKV * S * HD * 2);
    u16*   klb     = (u16*)  alloc((size_t)NKV * S * HD * 2);
    u16*   vhb     = (u16*)  alloc((size_t)NKV * S * HD * 2);
    u16*   vlb     = (u16*)  alloc((size_t)NKV * S * HD * 2);
    float* scores  = (float*)alloc((size_t)NH * S * S * 4);
    u16*   Phb     = (u16*)  alloc((size_t)NH * S * S * 2);
    u16*   Plb     = (u16*)  alloc((size_t)NH * S * S * 2);
    float* aof     = (float*)alloc((size_t)S * MDIM * 4);
    float* hbuf    = (float*)alloc((size_t)S * MDIM * 4);
    float* h2f     = (float*)alloc((size_t)S * MDIM * 4);
    u16*   h2b     = (u16*)  alloc((size_t)S * MDIM * 2);
    u16*   gatedS  = (u16*)  alloc((size_t)S * FF * 2);
    float* sharedO = (float*)alloc((size_t)S * MDIM * 4);
    float* logits  = (float*)alloc((size_t)S * NE * 4);
    int*   topi    = (int*)  alloc((size_t)S * TOPK * 4);
    float* wts     = (float*)alloc((size_t)S * TOPK * 4);
    int*   slots   = (int*)  alloc((size_t)S * TOPK * 4);
    int*   counts  = (int*)  alloc((size_t)NE * 4);
    int*   etok    = (int*)  alloc((size_t)NE * CAP * 4);
    u16*   egated  = (u16*)  alloc((size_t)NE * CAP * FF * 2);
    float* eo      = (float*)alloc((size_t)NE * CAP * MDIM * 4);

    // 1. RMS norm 1 -> hn (f32)
    k_rms<<<dim3(S), 256, 0, stream>>>(hidden, ln1_w, hnf, nullptr);
    // 2. QKV projection (3-term split)
    k_gemm_split<0><<<dim3(2048 / 64, S / 64), 256, 0, stream>>>(
        hnf, MDIM, qkv_w, 2048, qkvb, 2048, nullptr, S, MDIM);
    // 3. unpack + RoPE + q/k RMS -> pre-split bf16
    k_rope<<<dim3(S * NKV / 4), 256, 0, stream>>>(qkvb, cosb, sinb, qn_w, kn_w,
                                                  qhb, qlb, khb, klb, vhb, vlb);
    // 4. scores (lower triangle, 3-term)
    k_scores<<<dim3(16, 16, NH), 256, 0, stream>>>(qhb, qlb, khb, klb, scores);
    // 5. causal softmax -> P hi/lo
    k_softmax<<<dim3(S / 4, NH), 256, 0, stream>>>(scores, Phb, Plb);
    // 6. P @ V -> ao f32 (3-term)
    k_pv<<<dim3(16, NH), 256, 0, stream>>>(Phb, Plb, vhb, vlb, aof);
    // 7. O projection + residual -> h f32 (3-term)
    k_gemm_split<1><<<dim3(MDIM / 64, S / 64), 256, 0, stream>>>(
        aof, MDIM, o_w, MDIM, hbuf, MDIM, hidden, S, MDIM);
    // 8. RMS norm 2 -> h2 (f32 + bf16)
    k_rms<<<dim3(S), 256, 0, stream>>>(hbuf, ln2_w, h2f, h2b);
    // 9. router logits (f32)
    k_logits<<<dim3(S), 256, 0, stream>>>(h2f, gate_w, logits);
    // 10. softmax + top-8
    k_topk<<<dim3(S / 4), 256, 0, stream>>>(logits, topi, wts);
    // 11. capacity / slot assignment (parallel, exact reference semantics)
    k_slots<<<dim3(1), 512, 0, stream>>>(topi, slots, counts, etok);
    // 12. shared MLP up+gate (fused swiglu) -> gatedS bf16
    k_gemm_bf<128, true><<<dim3(FF / 64, S / 128), 256, 0, stream>>>(
        h2b, MDIM, 0, sgu_w, 2 * FF, 0, gatedS, FF, 0, S, MDIM, FF, nullptr, nullptr);
    // 13. shared MLP down -> sharedO f32
    k_gemm_bf<128, false><<<dim3(MDIM / 64, S / 128), 256, 0, stream>>>(
        gatedS, FF, 0, sdn_w, MDIM, 0, sharedO, MDIM, 0, S, FF, 0, nullptr, nullptr);
    // 14. expert up+gate (fused swiglu, gather-on-the-fly) -> egated bf16
    k_gemm_bf<160, true><<<dim3(FF / 64, (CAP + 159) / 160, NE), 256, 0, stream>>>(
        h2b, MDIM, 0, egu_w, 2 * FF, (long)MDIM * 2 * FF,
        egated, FF, (long)CAP * FF, CAP, MDIM, FF, counts, etok);
    // 15. expert down -> eo f32
    k_gemm_bf<160, false><<<dim3(MDIM / 64, (CAP + 159) / 160, NE), 256, 0, stream>>>(
        egated, FF, (long)CAP * FF, edn_w, MDIM, (long)FF * MDIM,
        eo, MDIM, (long)CAP * MDIM, CAP, FF, 0, counts, nullptr);
    // 16. combine: out = h + shared + moe
    k_combine<<<dim3(S), 256, 0, stream>>>(hbuf, sharedO, eo, topi, slots, wts, out);
}

// Round 5
// 1218.211 us; speedup vs baseline: 2.0631x; 1.2292x over previous
//
#include <hip/hip_runtime.h>

#define S 1024
#define MDIM 1024
#define NH 16
#define HD 64
#define NKV 8
#define FF 3072
#define NE 64
#define TOPK 8
#define CAP 256

typedef unsigned short u16;
typedef __attribute__((ext_vector_type(8))) short bf16x8;
typedef __attribute__((ext_vector_type(4))) float f32x4;

__device__ __forceinline__ u16 f2bf(float f) {
    union { float f; unsigned u; } x; x.f = f;
    unsigned r = x.u + 0x7FFFu + ((x.u >> 16) & 1u);
    return (u16)(r >> 16);
}
__device__ __forceinline__ float bf2f(u16 b) {
    union { unsigned u; float f; } x; x.u = ((unsigned)b) << 16;
    return x.f;
}
__device__ __forceinline__ void split1(float x, u16& h, u16& l) {
    h = f2bf(x);
    l = f2bf(x - bf2f(h));
}
// swizzled column (u16 units) for k-octet group G in row `row` of a [R][40] tile
__device__ __forceinline__ int swzcol(int row, int G) { return 8 * (G ^ ((row >> 3) & 3)); }

// ---------------- RMS norm 1: writes pre-split bf16 hi/lo ----------------
__global__ __launch_bounds__(256) void k_rms1(const float* __restrict__ x,
                                              const float* __restrict__ w,
                                              u16* __restrict__ ohi,
                                              u16* __restrict__ olo) {
    int s = blockIdx.x;
    const float* row = x + (size_t)s * MDIM;
    float v[4]; float ss = 0.f;
#pragma unroll
    for (int i = 0; i < 4; ++i) { v[i] = row[threadIdx.x + i * 256]; ss += v[i] * v[i]; }
#pragma unroll
    for (int of = 32; of; of >>= 1) ss += __shfl_xor(ss, of);
    __shared__ float red[4];
    int wid = threadIdx.x >> 6;
    if ((threadIdx.x & 63) == 0) red[wid] = ss;
    __syncthreads();
    float tot = red[0] + red[1] + red[2] + red[3];
    float sc = rsqrtf(tot * (1.f / MDIM) + 1e-6f);
#pragma unroll
    for (int i = 0; i < 4; ++i) {
        int c = threadIdx.x + i * 256;
        float ov = v[i] * sc * w[c];
        u16 hh, ll; split1(ov, hh, ll);
        ohi[(size_t)s * MDIM + c] = hh;
        olo[(size_t)s * MDIM + c] = ll;
    }
}

// ---------------- 3-term split GEMM, 2-phase pipelined: C = (Ahi+Alo)@B(f32) ----------------
// EPI: 0 = f32 out, 1 = f32 out + resid
template <int EPI>
__global__ __launch_bounds__(256) void k_gemm_split(
    const u16* __restrict__ Ahi, const u16* __restrict__ Alo, int lda,
    const float* __restrict__ B, int ldb,
    float* __restrict__ C, int ldc,
    const float* __restrict__ resid, int M, int K) {
    int m0 = blockIdx.y * 64;
    int n0 = blockIdx.x * 64;
    __shared__ u16 Ah[2][64][40];
    __shared__ u16 Al[2][64][40];
    __shared__ u16 Bh[2][64][40];
    __shared__ u16 Bl[2][64][40];
    int tid = threadIdx.x, lane = tid & 63, wid = tid >> 6;
    int wm = (wid >> 1) * 32, wn = (wid & 1) * 32;
    int rA = tid >> 2, GA = tid & 3, colA = swzcol(rA, GA);
    int nB = tid & 63, kbB = tid >> 6, colB = swzcol(nB, kbB);
    f32x4 acc[2][2] = {};

    bf16x8 rah, ral;
    float rb[8];
    auto loadT = [&](int k0) {
        size_t o = (size_t)(m0 + rA) * lda + k0 + GA * 8;
        rah = *(const bf16x8*)(Ahi + o);
        ral = *(const bf16x8*)(Alo + o);
        const float* bp = B + (size_t)(k0 + kbB * 8) * ldb + n0 + nB;
#pragma unroll
        for (int i = 0; i < 8; ++i) rb[i] = bp[(size_t)i * ldb];
    };
    auto writeT = [&](int b) {
        *(bf16x8*)&Ah[b][rA][colA] = rah;
        *(bf16x8*)&Al[b][rA][colA] = ral;
        bf16x8 hh, ll;
#pragma unroll
        for (int i = 0; i < 8; ++i) { u16 h, l; split1(rb[i], h, l); hh[i] = (short)h; ll[i] = (short)l; }
        *(bf16x8*)&Bh[b][nB][colB] = hh;
        *(bf16x8*)&Bl[b][nB][colB] = ll;
    };

    loadT(0);
    writeT(0);
    __syncthreads();
    int NT = K / 32;
    for (int t = 0; t < NT; ++t) {
        int c = t & 1;
        if (t + 1 < NT) loadT((t + 1) * 32);
        bf16x8 ah[2], al[2], bh[2], bl[2];
#pragma unroll
        for (int mi = 0; mi < 2; ++mi) {
            int r = wm + mi * 16 + (lane & 15);
            int cc = swzcol(r, lane >> 4);
            ah[mi] = *(const bf16x8*)&Ah[c][r][cc];
            al[mi] = *(const bf16x8*)&Al[c][r][cc];
        }
#pragma unroll
        for (int ni = 0; ni < 2; ++ni) {
            int r = wn + ni * 16 + (lane & 15);
            int cc = swzcol(r, lane >> 4);
            bh[ni] = *(const bf16x8*)&Bh[c][r][cc];
            bl[ni] = *(const bf16x8*)&Bl[c][r][cc];
        }
#pragma unroll
        for (int mi = 0; mi < 2; ++mi)
#pragma unroll
            for (int ni = 0; ni < 2; ++ni) {
                acc[mi][ni] = __builtin_amdgcn_mfma_f32_16x16x32_bf16(ah[mi], bh[ni], acc[mi][ni], 0, 0, 0);
                acc[mi][ni] = __builtin_amdgcn_mfma_f32_16x16x32_bf16(ah[mi], bl[ni], acc[mi][ni], 0, 0, 0);
                acc[mi][ni] = __builtin_amdgcn_mfma_f32_16x16x32_bf16(al[mi], bh[ni], acc[mi][ni], 0, 0, 0);
            }
        if (t + 1 < NT) {
            writeT(1 - c);
            __syncthreads();
        }
    }
#pragma unroll
    for (int mi = 0; mi < 2; ++mi)
#pragma unroll
        for (int ni = 0; ni < 2; ++ni)
#pragma unroll
            for (int r = 0; r < 4; ++r) {
                int row = m0 + wm + mi * 16 + (lane >> 4) * 4 + r;
                int col = n0 + wn + ni * 16 + (lane & 15);
                float v = acc[mi][ni][r];
                if constexpr (EPI == 1) v += resid[(size_t)row * ldc + col];
                C[(size_t)row * ldc + col] = v;
            }
}

// ---------------- 1-term bf16 GEMM, 2-phase pipelined (MLP path) ----------------
template <int TM, bool SWIGLU>
__global__ __launch_bounds__(256) void k_gemm_bf(
    const u16* __restrict__ A, int lda, long sAe,
    const float* __restrict__ B, int ldb, long sBe,
    void* __restrict__ Cv, int ldc, long sCe,
    int M, int K, int pairOff,
    const int* __restrict__ counts, const int* __restrict__ rowidx) {
    int e = blockIdx.z;
    if (counts) M = counts[e];
    int m0 = blockIdx.y * TM;
    if (m0 >= M) return;
    A += (size_t)e * sAe;
    B += (size_t)e * sBe;
    int n0 = blockIdx.x * 64;

    __shared__ u16 As[2][TM][40];
    __shared__ u16 Bs[2][64][40];
    __shared__ u16 B2s[2][SWIGLU ? 64 : 1][40];

    int tid = threadIdx.x, lane = tid & 63, wid = tid >> 6;
    constexpr int MF = TM / 32;
    constexpr int NRR = (TM + 63) / 64;
    int wm = (wid >> 1) * (TM / 2), wn = (wid & 1) * 32;

    f32x4 acc[MF][2] = {};
    f32x4 acc2[SWIGLU ? MF : 1][2] = {};

    long asrc[NRR];
#pragma unroll
    for (int rr = 0; rr < NRR; ++rr) {
        int r = rr * 64 + (tid >> 2);
        int gm = m0 + r;
        if (r < TM && gm < M)
            asrc[rr] = rowidx ? (long)rowidx[e * CAP + gm] : (long)gm;
        else
            asrc[rr] = -1;
    }
    int GA = tid & 3;
    int nB = tid & 63, kbB = tid >> 6;
    int colB = swzcol(nB, kbB);

    bf16x8 ra[NRR];
    float rb[8], rg[SWIGLU ? 8 : 1];
    auto loadT = [&](int k0) {
#pragma unroll
        for (int rr = 0; rr < NRR; ++rr) {
            bf16x8 v = {};
            if (asrc[rr] >= 0) v = *(const bf16x8*)(A + asrc[rr] * lda + k0 + GA * 8);
            ra[rr] = v;
        }
        const float* bp = B + (size_t)(k0 + kbB * 8) * ldb + n0 + nB;
#pragma unroll
        for (int i = 0; i < 8; ++i) rb[i] = bp[(size_t)i * ldb];
        if constexpr (SWIGLU) {
            const float* gp = bp + pairOff;
#pragma unroll
            for (int i = 0; i < 8; ++i) rg[i] = gp[(size_t)i * ldb];
        }
    };
    auto writeT = [&](int b) {
#pragma unroll
        for (int rr = 0; rr < NRR; ++rr) {
            int r = rr * 64 + (tid >> 2);
            if (r < TM) *(bf16x8*)&As[b][r][swzcol(r, GA)] = ra[rr];
        }
        bf16x8 v;
#pragma unroll
        for (int i = 0; i < 8; ++i) v[i] = (short)f2bf(rb[i]);
        *(bf16x8*)&Bs[b][nB][colB] = v;
        if constexpr (SWIGLU) {
            bf16x8 g;
#pragma unroll
            for (int i = 0; i < 8; ++i) g[i] = (short)f2bf(rg[i]);
            *(bf16x8*)&B2s[b][nB][colB] = g;
        }
    };

    loadT(0);
    writeT(0);
    __syncthreads();
    int NT = K / 32;
    for (int t = 0; t < NT; ++t) {
        int c = t & 1;
        if (t + 1 < NT) loadT((t + 1) * 32);
        bf16x8 af[MF], bfr[2], gfr[SWIGLU ? 2 : 1];
#pragma unroll
        for (int mi = 0; mi < MF; ++mi) {
            int r = wm + mi * 16 + (lane & 15);
            af[mi] = *(const bf16x8*)&As[c][r][swzcol(r, lane >> 4)];
        }
#pragma unroll
        for (int ni = 0; ni < 2; ++ni) {
            int r = wn + ni * 16 + (lane & 15);
            int cc = swzcol(r, lane >> 4);
            bfr[ni] = *(const bf16x8*)&Bs[c][r][cc];
            if constexpr (SWIGLU) gfr[ni] = *(const bf16x8*)&B2s[c][r][cc];
        }
#pragma unroll
        for (int mi = 0; mi < MF; ++mi)
#pragma unroll
            for (int ni = 0; ni < 2; ++ni) {
                acc[mi][ni] = __builtin_amdgcn_mfma_f32_16x16x32_bf16(af[mi], bfr[ni], acc[mi][ni], 0, 0, 0);
                if constexpr (SWIGLU)
                    acc2[mi][ni] = __builtin_amdgcn_mfma_f32_16x16x32_bf16(af[mi], gfr[ni], acc2[mi][ni], 0, 0, 0);
            }
        if (t + 1 < NT) {
            writeT(1 - c);
            __syncthreads();
        }
    }
#pragma unroll
    for (int mi = 0; mi < MF; ++mi)
#pragma unroll
        for (int ni = 0; ni < 2; ++ni)
#pragma unroll
            for (int r = 0; r < 4; ++r) {
                int row = m0 + wm + mi * 16 + (lane >> 4) * 4 + r;
                int col = n0 + wn + ni * 16 + (lane & 15);
                if (row >= M) continue;
                if constexpr (SWIGLU) {
                    float x1 = acc[mi][ni][r];
                    float x2 = acc2[mi][ni][r];
                    float val = x1 * (x2 / (1.f + __expf(-x2)));
                    ((u16*)Cv)[(size_t)e * sCe + (size_t)row * ldc + col] = f2bf(val);
                } else {
                    ((float*)Cv)[(size_t)e * sCe + (size_t)row * ldc + col] = acc[mi][ni][r];
                }
            }
}

// ---------------- unpack QKV + RoPE + q/k RMS norm -> pre-split bf16 hi/lo ----------------
__global__ __launch_bounds__(256) void k_rope(const float* __restrict__ qkv,
                                              const float* __restrict__ cosb,
                                              const float* __restrict__ sinb,
                                              const float* __restrict__ qn_w,
                                              const float* __restrict__ kn_w,
                                              u16* __restrict__ qh, u16* __restrict__ ql,
                                              u16* __restrict__ kh, u16* __restrict__ kl,
                                              u16* __restrict__ vh, u16* __restrict__ vl) {
    int wid = threadIdx.x >> 6, lane = threadIdx.x & 63;
    int idx = blockIdx.x * 4 + wid;   // 0..8191
    int s = idx >> 3, j = idx & 7;
    const float* base = qkv + (size_t)s * 2048 + j * 256;
    float c = cosb[s * HD + lane], sn = sinb[s * HD + lane];
    u16 hh, ll;
    split1(base[192 + lane], hh, ll);
    vh[((size_t)j * S + s) * HD + lane] = hh;
    vl[((size_t)j * S + s) * HD + lane] = ll;
#pragma unroll
    for (int r = 0; r < 3; ++r) {
        float x = base[r * 64 + lane];
        float xp = __shfl_xor(x, 32);
        float rot = (lane < 32) ? -xp : xp;
        float y = x * c + rot * sn;
        float ss = y * y;
#pragma unroll
        for (int o = 32; o; o >>= 1) ss += __shfl_xor(ss, o);
        float scale = rsqrtf(ss * (1.f / 64.f) + 1e-6f);
        float outv = y * scale * ((r == 2) ? kn_w[lane] : qn_w[lane]);
        split1(outv, hh, ll);
        if (r == 2) {
            kh[((size_t)j * S + s) * HD + lane] = hh;
            kl[((size_t)j * S + s) * HD + lane] = ll;
        } else {
            qh[((size_t)(j * 2 + r) * S + s) * HD + lane] = hh;
            ql[((size_t)(j * 2 + r) * S + s) * HD + lane] = ll;
        }
    }
}

// ---------------- scores = Q @ K^T * 0.125 (lower-triangle tiles), pre-split inputs ----------------
__global__ __launch_bounds__(256) void k_scores(const u16* __restrict__ qh, const u16* __restrict__ ql,
                                                const u16* __restrict__ kmh, const u16* __restrict__ kml,
                                                float* __restrict__ scores) {
    int kt = blockIdx.x, qt = blockIdx.y, h = blockIdx.z;
    if (kt > qt) return;
    size_t qoff = (size_t)h * S * HD;
    size_t koff = (size_t)(h >> 1) * S * HD;
    int lane = threadIdx.x & 63, wid = threadIdx.x >> 6;
    int wq = (wid >> 1) * 32, wk = (wid & 1) * 32;
    int q0 = qt * 64, k0 = kt * 64;
    f32x4 acc[2][2] = {};
#pragma unroll
    for (int ks = 0; ks < 2; ++ks) {
        bf16x8 ah[2], al[2], bh[2], bl[2];
#pragma unroll
        for (int mi = 0; mi < 2; ++mi) {
            size_t o = qoff + (size_t)(q0 + wq + mi * 16 + (lane & 15)) * HD + ks * 32 + (lane >> 4) * 8;
            ah[mi] = *(const bf16x8*)(qh + o);
            al[mi] = *(const bf16x8*)(ql + o);
        }
#pragma unroll
        for (int ni = 0; ni < 2; ++ni) {
            size_t o = koff + (size_t)(k0 + wk + ni * 16 + (lane & 15)) * HD + ks * 32 + (lane >> 4) * 8;
            bh[ni] = *(const bf16x8*)(kmh + o);
            bl[ni] = *(const bf16x8*)(kml + o);
        }
#pragma unroll
        for (int mi = 0; mi < 2; ++mi)
#pragma unroll
            for (int ni = 0; ni < 2; ++ni) {
                acc[mi][ni] = __builtin_amdgcn_mfma_f32_16x16x32_bf16(ah[mi], bh[ni], acc[mi][ni], 0, 0, 0);
                acc[mi][ni] = __builtin_amdgcn_mfma_f32_16x16x32_bf16(ah[mi], bl[ni], acc[mi][ni], 0, 0, 0);
                acc[mi][ni] = __builtin_amdgcn_mfma_f32_16x16x32_bf16(al[mi], bh[ni], acc[mi][ni], 0, 0, 0);
            }
    }
#pragma unroll
    for (int mi = 0; mi < 2; ++mi)
#pragma unroll
        for (int ni = 0; ni < 2; ++ni)
#pragma unroll
            for (int r = 0; r < 4; ++r) {
                int row = q0 + wq + mi * 16 + (lane >> 4) * 4 + r;
                int col = k0 + wk + ni * 16 + (lane & 15);
                scores[(size_t)h * S * S + (size_t)row * S + col] = acc[mi][ni][r] * 0.125f;
            }
}

// ---------------- causal softmax f32 -> P bf16 hi/lo (writes only up to diag tile) ----------------
__global__ __launch_bounds__(256) void k_softmax(const float* __restrict__ scores,
                                                 u16* __restrict__ Ph, u16* __restrict__ Pl) {
    int wid = threadIdx.x >> 6, lane = threadIdx.x & 63;
    int q = blockIdx.x * 4 + wid, h = blockIdx.y;
    const float* row = scores + (size_t)h * S * S + (size_t)q * S;
    size_t po = (size_t)h * S * S + (size_t)q * S;
    int L = q + 1;
    int wlim = ((q >> 6) + 1) * 64;   // end of diagonal tile
    float v[16];
    float mx = -1e30f;
#pragma unroll
    for (int i = 0; i < 16; ++i) {
        int idx = lane + i * 64;
        v[i] = (idx < L) ? row[idx] : -1e30f;
        mx = fmaxf(mx, v[i]);
    }
#pragma unroll
    for (int o = 32; o; o >>= 1) mx = fmaxf(mx, __shfl_xor(mx, o));
    float sum = 0.f;
#pragma unroll
    for (int i = 0; i < 16; ++i) {
        int idx = lane + i * 64;
        v[i] = (idx < L) ? __expf(v[i] - mx) : 0.f;
        sum += v[i];
    }
#pragma unroll
    for (int o = 32; o; o >>= 1) sum += __shfl_xor(sum, o);
    float inv = 1.f / sum;
#pragma unroll
    for (int i = 0; i < 16; ++i) {
        int idx = lane + i * 64;
        if (idx < wlim) {
            u16 hh, ll;
            split1(v[i] * inv, hh, ll);
            Ph[po + idx] = hh;
            Pl[po + idx] = ll;
        }
    }
}

// ---------------- O = P @ V (pre-split), writes ao bf16 hi/lo in (s, h*64+d) layout ----------------
__global__ __launch_bounds__(256) void k_pv(const u16* __restrict__ Ph, const u16* __restrict__ Pl,
                                            const u16* __restrict__ vmh, const u16* __restrict__ vml,
                                            u16* __restrict__ aoh, u16* __restrict__ aol) {
    int qt = blockIdx.x, h = blockIdx.y;
    size_t poff = (size_t)h * S * S;
    size_t voff = (size_t)(h >> 1) * S * HD;
    __shared__ u16 Vh[64][72];
    __shared__ u16 Vl[64][72];
    int tid = threadIdx.x, lane = tid & 63, wid = tid >> 6;
    int wq = (wid >> 1) * 32, wd = (wid & 1) * 32;
    int q0 = qt * 64;
    f32x4 acc[2][2] = {};
    int kmax = (qt + 1) * 64;
    for (int kc = 0; kc < kmax; kc += 64) {
#pragma unroll
        for (int i = 0; i < 16; ++i) {
            int idx = tid + i * 256;
            int kr = idx >> 6, d = idx & 63;
            Vh[d][kr] = vmh[voff + (size_t)(kc + kr) * HD + d];
            Vl[d][kr] = vml[voff + (size_t)(kc + kr) * HD + d];
        }
        __syncthreads();
#pragma unroll
        for (int ks = 0; ks < 2; ++ks) {
            bf16x8 ph[2], pl[2], vh[2], vl[2];
#pragma unroll
            for (int mi = 0; mi < 2; ++mi) {
                size_t o = poff + (size_t)(q0 + wq + mi * 16 + (lane & 15)) * S + kc + ks * 32 + (lane >> 4) * 8;
                ph[mi] = *(const bf16x8*)(Ph + o);
                pl[mi] = *(const bf16x8*)(Pl + o);
            }
#pragma unroll
            for (int ni = 0; ni < 2; ++ni) {
                vh[ni] = *(const bf16x8*)&Vh[wd + ni * 16 + (lane & 15)][ks * 32 + (lane >> 4) * 8];
                vl[ni] = *(const bf16x8*)&Vl[wd + ni * 16 + (lane & 15)][ks * 32 + (lane >> 4) * 8];
            }
#pragma unroll
            for (int mi = 0; mi < 2; ++mi)
#pragma unroll
                for (int ni = 0; ni < 2; ++ni) {
                    acc[mi][ni] = __builtin_amdgcn_mfma_f32_16x16x32_bf16(ph[mi], vh[ni], acc[mi][ni], 0, 0, 0);
                    acc[mi][ni] = __builtin_amdgcn_mfma_f32_16x16x32_bf16(ph[mi], vl[ni], acc[mi][ni], 0, 0, 0);
                    acc[mi][ni] = __builtin_amdgcn_mfma_f32_16x16x32_bf16(pl[mi], vh[ni], acc[mi][ni], 0, 0, 0);
                }
        }
        __syncthreads();
    }
#pragma unroll
    for (int mi = 0; mi < 2; ++mi)
#pragma unroll
        for (int ni = 0; ni < 2; ++ni)
#pragma unroll
            for (int r = 0; r < 4; ++r) {
                int row = q0 + wq + mi * 16 + (lane >> 4) * 4 + r;
                int col = wd + ni * 16 + (lane & 15);
                u16 hh, ll; split1(acc[mi][ni][r], hh, ll);
                aoh[(size_t)row * MDIM + h * HD + col] = hh;
                aol[(size_t)row * MDIM + h * HD + col] = ll;
            }
}

// ---------------- fused RMS norm 2 + router logits + top-8 ----------------
__global__ __launch_bounds__(256) void k_rms2_router(const float* __restrict__ h,
                                                     const float* __restrict__ w,
                                                     const float* __restrict__ gw,
                                                     u16* __restrict__ h2b,
                                                     int* __restrict__ topi,
                                                     float* __restrict__ wts) {
    __shared__ float xr[1024];
    __shared__ float part[4][64];
    __shared__ float red[4];
    int s = blockIdx.x, tid = threadIdx.x;
    const float* row = h + (size_t)s * MDIM;
    float v[4]; float ss = 0.f;
#pragma unroll
    for (int i = 0; i < 4; ++i) { v[i] = row[tid + i * 256]; ss += v[i] * v[i]; }
#pragma unroll
    for (int of = 32; of; of >>= 1) ss += __shfl_xor(ss, of);
    if ((tid & 63) == 0) red[tid >> 6] = ss;
    __syncthreads();
    float tot = red[0] + red[1] + red[2] + red[3];
    float sc = rsqrtf(tot * (1.f / MDIM) + 1e-6f);
#pragma unroll
    for (int i = 0; i < 4; ++i) {
        int c = tid + i * 256;
        float ov = v[i] * sc * w[c];
        xr[c] = ov;
        h2b[(size_t)s * MDIM + c] = f2bf(ov);
    }
    __syncthreads();
    int e = tid & 63, qq = tid >> 6;
    float acc = 0.f;
    for (int i = 0; i < 256; ++i) acc += xr[qq * 256 + i] * gw[(size_t)(qq * 256 + i) * NE + e];
    part[qq][e] = acc;
    __syncthreads();
    if (tid < 64) {
        int lane = tid;
        float lg = part[0][lane] + part[1][lane] + part[2][lane] + part[3][lane];
        float mx = lg;
#pragma unroll
        for (int o = 32; o; o >>= 1) mx = fmaxf(mx, __shfl_xor(mx, o));
        float ex = __expf(lg - mx);
        float sum = ex;
#pragma unroll
        for (int o = 32; o; o >>= 1) sum += __shfl_xor(sum, o);
        float g = ex / sum;
        float cur = g;
        float tv[TOPK]; int ti[TOPK];
        float tsum = 0.f;
#pragma unroll
        for (int k = 0; k < TOPK; ++k) {
            float vv = cur; int ii = lane;
#pragma unroll
            for (int o = 32; o; o >>= 1) {
                float vo = __shfl_xor(vv, o);
                int io = __shfl_xor(ii, o);
                if (vo > vv || (vo == vv && io < ii)) { vv = vo; ii = io; }
            }
            tv[k] = vv; ti[k] = ii; tsum += vv;
            if (lane == ii) cur = -1.f;
        }
        float gs = fmaxf(tsum, 1.1920929e-07f);
        if (lane == 0) {
#pragma unroll
            for (int k = 0; k < TOPK; ++k) {
                topi[s * TOPK + k] = ti[k];
                wts[s * TOPK + k] = tv[k] / gs;
            }
        }
    }
}

// ---------------- parallel rank-major priority / capacity assignment ----------------
__global__ __launch_bounds__(512) void k_slots(const int* __restrict__ topi, int* __restrict__ slots,
                                               int* __restrict__ counts, int* __restrict__ etok) {
    __shared__ int tl[S * TOPK];
    __shared__ int cnt[TOPK][NE];
    __shared__ int base[TOPK][NE];
    int tid = threadIdx.x;
    for (int i = tid; i < S * TOPK; i += 512) tl[i] = topi[i];
    ((int*)cnt)[tid] = 0;   // 512 == TOPK*NE
    __syncthreads();
    for (int i = tid; i < S * TOPK; i += 512)
        atomicAdd(&cnt[i & 7][tl[i]], 1);
    __syncthreads();
    if (tid < NE) {
        int acc = 0;
#pragma unroll
        for (int k = 0; k < TOPK; ++k) { base[k][tid] = acc; acc += cnt[k][tid]; }
        counts[tid] = acc < CAP ? acc : CAP;
    }
    __syncthreads();
    int k = tid >> 6, e = tid & 63;
    int rank = base[k][e];
    for (int s = 0; s < S; ++s) {
        if (tl[s * TOPK + k] == e) {
            if (rank < CAP) { slots[s * TOPK + k] = rank; etok[e * CAP + rank] = s; }
            else slots[s * TOPK + k] = -1;
            rank++;
        }
    }
}

// ---------------- final combine: out = h + shared + sum_k w_k * eo[e_k, slot_k] ----------------
__global__ __launch_bounds__(256) void k_combine(const float* __restrict__ h,
                                                 const float* __restrict__ sh,
                                                 const float* __restrict__ eo,
                                                 const int* __restrict__ topi,
                                                 const int* __restrict__ slots,
                                                 const float* __restrict__ wts,
                                                 float* __restrict__ out) {
    int s = blockIdx.x, t = threadIdx.x;
    float w[TOPK]; int off[TOPK];
#pragma unroll
    for (int k = 0; k < TOPK; ++k) {
        int sl = slots[s * TOPK + k];
        int ee = topi[s * TOPK + k];
        w[k] = wts[s * TOPK + k];
        off[k] = (sl >= 0) ? ee * CAP + sl : -1;
    }
#pragma unroll
    for (int i = 0; i < 4; ++i) {
        int col = t + i * 256;
        float acc = h[(size_t)s * MDIM + col] + sh[(size_t)s * MDIM + col];
#pragma unroll
        for (int k = 0; k < TOPK; ++k)
            if (off[k] >= 0) acc += w[k] * eo[(size_t)off[k] * MDIM + col];
        out[(size_t)s * MDIM + col] = acc;
    }
}

extern "C" void kernel_launch(void* const* d_in, const int* in_sizes, int n_in,
                              void* d_out, int out_size, void* d_ws, size_t ws_size,
                              hipStream_t stream) {
    (void)in_sizes; (void)n_in; (void)out_size; (void)ws_size;
    const float* hidden = (const float*)d_in[0];
    const float* cosb   = (const float*)d_in[1];
    const float* sinb   = (const float*)d_in[2];
    const float* ln1_w  = (const float*)d_in[3];
    const float* ln2_w  = (const float*)d_in[4];
    const float* qkv_w  = (const float*)d_in[5];
    const float* o_w    = (const float*)d_in[6];
    const float* qn_w   = (const float*)d_in[7];
    const float* kn_w   = (const float*)d_in[8];
    const float* sgu_w  = (const float*)d_in[9];
    const float* sdn_w  = (const float*)d_in[10];
    const float* gate_w = (const float*)d_in[11];
    const float* egu_w  = (const float*)d_in[12];
    const float* edn_w  = (const float*)d_in[13];
    float* out = (float*)d_out;

    char* ws = (char*)d_ws;
    size_t off = 0;
    auto alloc = [&](size_t bytes) -> void* {
        void* p = ws + off;
        off = (off + bytes + 255) & ~(size_t)255;
        return p;
    };
    u16*   hn_hi   = (u16*)  alloc((size_t)S * MDIM * 2);
    u16*   hn_lo   = (u16*)  alloc((size_t)S * MDIM * 2);
    float* qkvb    = (float*)alloc((size_t)S * 2048 * 4);
    u16*   qhb     = (u16*)  alloc((size_t)NH * S * HD * 2);
    u16*   qlb     = (u16*)  alloc((size_t)NH * S * HD * 2);
    u16*   khb     = (u16*)  alloc((size_t)NKV * S * HD * 2);
    u16*   klb     = (u16*)  alloc((size_t)NKV * S * HD * 2);
    u16*   vhb     = (u16*)  alloc((size_t)NKV * S * HD * 2);
    u16*   vlb     = (u16*)  alloc((size_t)NKV * S * HD * 2);
    float* scores  = (float*)alloc((size_t)NH * S * S * 4);
    u16*   Phb     = (u16*)  alloc((size_t)NH * S * S * 2);
    u16*   Plb     = (u16*)  alloc((size_t)NH * S * S * 2);
    u16*   ao_hi   = (u16*)  alloc((size_t)S * MDIM * 2);
    u16*   ao_lo   = (u16*)  alloc((size_t)S * MDIM * 2);
    float* hbuf    = (float*)alloc((size_t)S * MDIM * 4);
    u16*   h2b     = (u16*)  alloc((size_t)S * MDIM * 2);
    u16*   gatedS  = (u16*)  alloc((size_t)S * FF * 2);
    float* sharedO = (float*)alloc((size_t)S * MDIM * 4);
    int*   topi    = (int*)  alloc((size_t)S * TOPK * 4);
    float* wts     = (float*)alloc((size_t)S * TOPK * 4);
    int*   slots   = (int*)  alloc((size_t)S * TOPK * 4);
    int*   counts  = (int*)  alloc((size_t)NE * 4);
    int*   etok    = (int*)  alloc((size_t)NE * CAP * 4);
    u16*   egated  = (u16*)  alloc((size_t)NE * CAP * FF * 2);
    float* eo      = (float*)alloc((size_t)NE * CAP * MDIM * 4);

    // 1. RMS norm 1 -> hn hi/lo
    k_rms1<<<dim3(S), 256, 0, stream>>>(hidden, ln1_w, hn_hi, hn_lo);
    // 2. QKV projection (3-term split, pipelined)
    k_gemm_split<0><<<dim3(2048 / 64, S / 64), 256, 0, stream>>>(
        hn_hi, hn_lo, MDIM, qkv_w, 2048, qkvb, 2048, nullptr, S, MDIM);
    // 3. unpack + RoPE + q/k RMS -> pre-split bf16
    k_rope<<<dim3(S * NKV / 4), 256, 0, stream>>>(qkvb, cosb, sinb, qn_w, kn_w,
                                                  qhb, qlb, khb, klb, vhb, vlb);
    // 4. scores (lower triangle, 3-term)
    k_scores<<<dim3(16, 16, NH), 256, 0, stream>>>(qhb, qlb, khb, klb, scores);
    // 5. causal softmax -> P hi/lo
    k_softmax<<<dim3(S / 4, NH), 256, 0, stream>>>(scores, Phb, Plb);
    // 6. P @ V -> ao hi/lo (3-term)
    k_pv<<<dim3(16, NH), 256, 0, stream>>>(Phb, Plb, vhb, vlb, ao_hi, ao_lo);
    // 7. O projection + residual -> h f32 (3-term, pipelined)
    k_gemm_split<1><<<dim3(MDIM / 64, S / 64), 256, 0, stream>>>(
        ao_hi, ao_lo, MDIM, o_w, MDIM, hbuf, MDIM, hidden, S, MDIM);
    // 8. fused RMS norm 2 + router logits + top-8
    k_rms2_router<<<dim3(S), 256, 0, stream>>>(hbuf, ln2_w, gate_w, h2b, topi, wts);
    // 9. capacity / slot assignment
    k_slots<<<dim3(1), 512, 0, stream>>>(topi, slots, counts, etok);
    // 10. shared MLP up+gate (fused swiglu, pipelined) -> gatedS bf16
    k_gemm_bf<128, true><<<dim3(FF / 64, S / 128), 256, 0, stream>>>(
        h2b, MDIM, 0, sgu_w, 2 * FF, 0, gatedS, FF, 0, S, MDIM, FF, nullptr, nullptr);
    // 11. shared MLP down (pipelined) -> sharedO f32
    k_gemm_bf<128, false><<<dim3(MDIM / 64, S / 128), 256, 0, stream>>>(
        gatedS, FF, 0, sdn_w, MDIM, 0, sharedO, MDIM, 0, S, FF, 0, nullptr, nullptr);
    // 12. expert up+gate (fused swiglu, gather-on-the-fly, pipelined) -> egated bf16
    k_gemm_bf<160, true><<<dim3(FF / 64, (CAP + 159) / 160, NE), 256, 0, stream>>>(
        h2b, MDIM, 0, egu_w, 2 * FF, (long)MDIM * 2 * FF,
        egated, FF, (long)CAP * FF, CAP, MDIM, FF, counts, etok);
    // 13. expert down (pipelined) -> eo f32
    k_gemm_bf<160, false><<<dim3(MDIM / 64, (CAP + 159) / 160, NE), 256, 0, stream>>>(
        egated, FF, (long)CAP * FF, edn_w, MDIM, (long)FF * MDIM,
        eo, MDIM, (long)CAP * MDIM, CAP, FF, 0, counts, nullptr);
    // 14. combine: out = h + shared + moe
    k_combine<<<dim3(S), 256, 0, stream>>>(hbuf, sharedO, eo, topi, slots, wts, out);
}

// Round 6
// 1032.912 us; speedup vs baseline: 2.4332x; 1.1794x over previous
//
#include <hip/hip_runtime.h>

#define S 1024
#define MDIM 1024
#define NH 16
#define HD 64
#define NKV 8
#define FF 3072
#define NE 64
#define TOPK 8
#define CAP 256

typedef unsigned short u16;
typedef __attribute__((ext_vector_type(8))) short bf16x8;
typedef __attribute__((ext_vector_type(4))) float f32x4;

__device__ __forceinline__ u16 f2bf(float f) {
    union { float f; unsigned u; } x; x.f = f;
    unsigned r = x.u + 0x7FFFu + ((x.u >> 16) & 1u);
    return (u16)(r >> 16);
}
__device__ __forceinline__ float bf2f(u16 b) {
    union { unsigned u; float f; } x; x.u = ((unsigned)b) << 16;
    return x.f;
}
__device__ __forceinline__ void split1(float x, u16& h, u16& l) {
    h = f2bf(x);
    l = f2bf(x - bf2f(h));
}
// swizzled column (u16 units) for k-octet G in row `row` of a [R][40] B-tile
__device__ __forceinline__ int swzcol(int row, int G) { return 8 * (G ^ ((row >> 3) & 3)); }

// 16B global->LDS DMA (dest = wave-uniform base + lane*16)
__device__ __forceinline__ void gl_lds16(const u16* g, u16* l) {
    __builtin_amdgcn_global_load_lds(
        (const __attribute__((address_space(1))) unsigned int*)g,
        (__attribute__((address_space(3))) unsigned int*)l, 16, 0, 0);
}

// ---------------- RMS norm 1: writes pre-split bf16 hi/lo ----------------
__global__ __launch_bounds__(256) void k_rms1(const float* __restrict__ x,
                                              const float* __restrict__ w,
                                              u16* __restrict__ ohi,
                                              u16* __restrict__ olo) {
    int s = blockIdx.x;
    const float* row = x + (size_t)s * MDIM;
    float v[4]; float ss = 0.f;
#pragma unroll
    for (int i = 0; i < 4; ++i) { v[i] = row[threadIdx.x + i * 256]; ss += v[i] * v[i]; }
#pragma unroll
    for (int of = 32; of; of >>= 1) ss += __shfl_xor(ss, of);
    __shared__ float red[4];
    int wid = threadIdx.x >> 6;
    if ((threadIdx.x & 63) == 0) red[wid] = ss;
    __syncthreads();
    float tot = red[0] + red[1] + red[2] + red[3];
    float sc = rsqrtf(tot * (1.f / MDIM) + 1e-6f);
#pragma unroll
    for (int i = 0; i < 4; ++i) {
        int c = threadIdx.x + i * 256;
        float ov = v[i] * sc * w[c];
        u16 hh, ll; split1(ov, hh, ll);
        ohi[(size_t)s * MDIM + c] = hh;
        olo[(size_t)s * MDIM + c] = ll;
    }
}

// ---------------- 3-term split GEMM, pipelined + gload_lds A: C = (Ahi+Alo)@B(f32) ----------------
// EPI: 0 = f32 out, 1 = f32 out + resid
template <int EPI>
__global__ __launch_bounds__(256) void k_gemm_split(
    const u16* __restrict__ Ahi, const u16* __restrict__ Alo, int lda,
    const float* __restrict__ B, int ldb,
    float* __restrict__ C, int ldc,
    const float* __restrict__ resid, int M, int K) {
    int m0 = blockIdx.y * 64;
    int n0 = blockIdx.x * 64;
    __shared__ u16 Ah[2][64][32];
    __shared__ u16 Al[2][64][32];
    __shared__ u16 Bh[2][64][40];
    __shared__ u16 Bl[2][64][40];
    int tid = threadIdx.x, lane = tid & 63, wid = tid >> 6;
    int wm = (wid >> 1) * 32, wn = (wid & 1) * 32;
    f32x4 acc[2][2] = {};

    // A sources: wave w stages 16-row chunk w of both hi and lo, source octet pre-swizzled
    int rt = wid * 16 + (lane >> 2);
    int gsrc = (lane & 3) ^ ((lane >> 4) & 3);
    const u16* ahb = Ahi + (size_t)(m0 + rt) * lda + gsrc * 8;
    const u16* alb = Alo + (size_t)(m0 + rt) * lda + gsrc * 8;

    int nB = tid & 63, kbB = tid >> 6;
    int colB = swzcol(nB, kbB);
    float rb[8];
    auto loadB = [&](int k0) {
        const float* bp = B + (size_t)(k0 + kbB * 8) * ldb + n0 + nB;
#pragma unroll
        for (int i = 0; i < 8; ++i) rb[i] = bp[(size_t)i * ldb];
    };
    auto stageA = [&](int b, int k0) {
        gl_lds16(ahb + k0, &Ah[b][wid * 16][0]);
        gl_lds16(alb + k0, &Al[b][wid * 16][0]);
    };
    auto writeB = [&](int b) {
        bf16x8 hh, ll;
#pragma unroll
        for (int i = 0; i < 8; ++i) { u16 h, l; split1(rb[i], h, l); hh[i] = (short)h; ll[i] = (short)l; }
        *(bf16x8*)&Bh[b][nB][colB] = hh;
        *(bf16x8*)&Bl[b][nB][colB] = ll;
    };

    loadB(0); stageA(0, 0); writeB(0);
    __syncthreads();
    int NT = K / 32;
    for (int t = 0; t < NT; ++t) {
        int c = t & 1;
        if (t + 1 < NT) { loadB((t + 1) * 32); stageA(1 - c, (t + 1) * 32); }
        bf16x8 ah[2], al[2], bh[2], bl[2];
#pragma unroll
        for (int mi = 0; mi < 2; ++mi) {
            int r = wm + mi * 16 + (lane & 15);
            int cA = 8 * ((lane >> 4) ^ ((r >> 2) & 3));
            ah[mi] = *(const bf16x8*)&Ah[c][r][cA];
            al[mi] = *(const bf16x8*)&Al[c][r][cA];
        }
#pragma unroll
        for (int ni = 0; ni < 2; ++ni) {
            int r = wn + ni * 16 + (lane & 15);
            int cc = swzcol(r, lane >> 4);
            bh[ni] = *(const bf16x8*)&Bh[c][r][cc];
            bl[ni] = *(const bf16x8*)&Bl[c][r][cc];
        }
#pragma unroll
        for (int mi = 0; mi < 2; ++mi)
#pragma unroll
            for (int ni = 0; ni < 2; ++ni) {
                acc[mi][ni] = __builtin_amdgcn_mfma_f32_16x16x32_bf16(ah[mi], bh[ni], acc[mi][ni], 0, 0, 0);
                acc[mi][ni] = __builtin_amdgcn_mfma_f32_16x16x32_bf16(ah[mi], bl[ni], acc[mi][ni], 0, 0, 0);
                acc[mi][ni] = __builtin_amdgcn_mfma_f32_16x16x32_bf16(al[mi], bh[ni], acc[mi][ni], 0, 0, 0);
            }
        if (t + 1 < NT) { writeB(1 - c); __syncthreads(); }
    }
#pragma unroll
    for (int mi = 0; mi < 2; ++mi)
#pragma unroll
        for (int ni = 0; ni < 2; ++ni)
#pragma unroll
            for (int r = 0; r < 4; ++r) {
                int row = m0 + wm + mi * 16 + (lane >> 4) * 4 + r;
                int col = n0 + wn + ni * 16 + (lane & 15);
                float v = acc[mi][ni][r];
                if constexpr (EPI == 1) v += resid[(size_t)row * ldc + col];
                C[(size_t)row * ldc + col] = v;
            }
}

// ---------------- 1-term bf16 GEMM, pipelined + gload_lds A; merged expert+shared ----------------
// z < NE: expert z (M=counts[z], optional rowidx gather). z >= NE: shared GEMM m-tile slot.
template <int TM, int TN, bool SWIGLU>
__global__ __launch_bounds__(256) void k_gemm_bf(
    const u16* __restrict__ A, int lda, long sAe,
    const float* __restrict__ B, long sBe, int ldb,
    u16* __restrict__ C, int ldc, long sCe,
    int K, int pairOff,
    const int* __restrict__ counts, const int* __restrict__ rowidx,
    const u16* __restrict__ Ash, const float* __restrict__ Bsh,
    u16* __restrict__ Csh, int Msh) {
    int z = blockIdx.z;
    int tid = threadIdx.x, lane = tid & 63, wid = tid >> 6;
    int M, m0;
    const int* ridx = nullptr;
    if (z >= NE) {
        int mslot = (z - NE) * 2 + blockIdx.y;
        m0 = mslot * TM;
        M = Msh;
        A = Ash; B = Bsh; C = Csh;
        if (m0 >= M) return;
    } else {
        M = counts[z];
        m0 = blockIdx.y * TM;
        if (m0 >= M) return;
        A += (size_t)z * sAe;
        B += (size_t)z * sBe;
        C += (size_t)z * sCe;
        if (rowidx) ridx = rowidx + z * CAP;
    }
    int n0 = blockIdx.x * TN;

    __shared__ u16 As[2][TM][32];
    __shared__ u16 Bs[2][TN][40];
    __shared__ u16 B2s[2][SWIGLU ? TN : 1][40];

    constexpr int MF = TM / 32;
    constexpr int NI = TN / 32;
    int wm = (wid >> 1) * (TM / 2), wn = (wid & 1) * (TN / 2);

    f32x4 acc[MF][NI] = {};
    f32x4 acc2[SWIGLU ? MF : 1][NI] = {};

    // A: 16-row chunks via gload_lds, pre-swizzled source octet
    constexpr int NCH = TM / 16;
    constexpr int CPW = (NCH + 3) / 4;
    int arow_in = lane >> 2;
    int gsrc = (lane & 3) ^ ((lane >> 4) & 3);
    const u16* abase[CPW];
#pragma unroll
    for (int i = 0; i < CPW; ++i) {
        int ch = wid + i * 4;
        const u16* p = A;
        if (ch < NCH) {
            int rti = ch * 16 + arow_in;
            int gm = m0 + rti;
            long grow = (gm < M) ? (ridx ? (long)ridx[gm] : (long)gm) : 0;
            p = A + grow * (size_t)lda + gsrc * 8;
        }
        abase[i] = p;
    }
    auto stageA = [&](int b, int k0) {
#pragma unroll
        for (int i = 0; i < CPW; ++i) {
            int ch = wid + i * 4;
            if (ch < NCH) gl_lds16(abase[i] + k0, &As[b][ch * 16][0]);
        }
    };

    constexpr int NKG = 256 / TN;       // thread k-groups
    constexpr int OPT = 4 / NKG;        // octets per thread
    int nB = tid % TN, kgB = tid / TN;
    float rb[OPT][8], rg[SWIGLU ? OPT : 1][8];
    auto loadB = [&](int k0) {
        const float* bp = B + (size_t)(k0 + kgB * OPT * 8) * ldb + n0 + nB;
#pragma unroll
        for (int j = 0; j < OPT; ++j)
#pragma unroll
            for (int i = 0; i < 8; ++i) {
                rb[j][i] = bp[(size_t)(j * 8 + i) * ldb];
                if constexpr (SWIGLU) rg[j][i] = bp[(size_t)(j * 8 + i) * ldb + pairOff];
            }
    };
    auto writeB = [&](int b) {
#pragma unroll
        for (int j = 0; j < OPT; ++j) {
            int col = swzcol(nB, kgB * OPT + j);
            bf16x8 v;
#pragma unroll
            for (int i = 0; i < 8; ++i) v[i] = (short)f2bf(rb[j][i]);
            *(bf16x8*)&Bs[b][nB][col] = v;
            if constexpr (SWIGLU) {
                bf16x8 g;
#pragma unroll
                for (int i = 0; i < 8; ++i) g[i] = (short)f2bf(rg[j][i]);
                *(bf16x8*)&B2s[b][nB][col] = g;
            }
        }
    };

    loadB(0); stageA(0, 0); writeB(0);
    __syncthreads();
    int NT = K / 32;
    for (int t = 0; t < NT; ++t) {
        int c = t & 1;
        if (t + 1 < NT) { loadB((t + 1) * 32); stageA(1 - c, (t + 1) * 32); }
        bf16x8 af[MF], bfr[NI], gfr[SWIGLU ? NI : 1];
#pragma unroll
        for (int mi = 0; mi < MF; ++mi) {
            int r = wm + mi * 16 + (lane & 15);
            int cA = 8 * ((lane >> 4) ^ ((r >> 2) & 3));
            af[mi] = *(const bf16x8*)&As[c][r][cA];
        }
#pragma unroll
        for (int ni = 0; ni < NI; ++ni) {
            int r = wn + ni * 16 + (lane & 15);
            int cB = swzcol(r, lane >> 4);
            bfr[ni] = *(const bf16x8*)&Bs[c][r][cB];
            if constexpr (SWIGLU) gfr[ni] = *(const bf16x8*)&B2s[c][r][cB];
        }
#pragma unroll
        for (int mi = 0; mi < MF; ++mi)
#pragma unroll
            for (int ni = 0; ni < NI; ++ni) {
                acc[mi][ni] = __builtin_amdgcn_mfma_f32_16x16x32_bf16(af[mi], bfr[ni], acc[mi][ni], 0, 0, 0);
                if constexpr (SWIGLU)
                    acc2[mi][ni] = __builtin_amdgcn_mfma_f32_16x16x32_bf16(af[mi], gfr[ni], acc2[mi][ni], 0, 0, 0);
            }
        if (t + 1 < NT) { writeB(1 - c); __syncthreads(); }
    }
#pragma unroll
    for (int mi = 0; mi < MF; ++mi)
#pragma unroll
        for (int ni = 0; ni < NI; ++ni)
#pragma unroll
            for (int r = 0; r < 4; ++r) {
                int row = m0 + wm + mi * 16 + (lane >> 4) * 4 + r;
                int col = n0 + wn + ni * 16 + (lane & 15);
                if (row >= M) continue;
                float x1 = acc[mi][ni][r];
                if constexpr (SWIGLU) {
                    float x2 = acc2[mi][ni][r];
                    x1 = x1 * (x2 / (1.f + __expf(-x2)));
                }
                C[(size_t)row * ldc + col] = f2bf(x1);
            }
}

// ---------------- unpack QKV + RoPE + q/k RMS norm -> pre-split bf16 hi/lo ----------------
__global__ __launch_bounds__(256) void k_rope(const float* __restrict__ qkv,
                                              const float* __restrict__ cosb,
                                              const float* __restrict__ sinb,
                                              const float* __restrict__ qn_w,
                                              const float* __restrict__ kn_w,
                                              u16* __restrict__ qh, u16* __restrict__ ql,
                                              u16* __restrict__ kh, u16* __restrict__ kl,
                                              u16* __restrict__ vh, u16* __restrict__ vl) {
    int wid = threadIdx.x >> 6, lane = threadIdx.x & 63;
    int idx = blockIdx.x * 4 + wid;   // 0..8191
    int s = idx >> 3, j = idx & 7;
    const float* base = qkv + (size_t)s * 2048 + j * 256;
    float c = cosb[s * HD + lane], sn = sinb[s * HD + lane];
    u16 hh, ll;
    split1(base[192 + lane], hh, ll);
    vh[((size_t)j * S + s) * HD + lane] = hh;
    vl[((size_t)j * S + s) * HD + lane] = ll;
#pragma unroll
    for (int r = 0; r < 3; ++r) {
        float x = base[r * 64 + lane];
        float xp = __shfl_xor(x, 32);
        float rot = (lane < 32) ? -xp : xp;
        float y = x * c + rot * sn;
        float ss = y * y;
#pragma unroll
        for (int o = 32; o; o >>= 1) ss += __shfl_xor(ss, o);
        float scale = rsqrtf(ss * (1.f / 64.f) + 1e-6f);
        float outv = y * scale * ((r == 2) ? kn_w[lane] : qn_w[lane]);
        split1(outv, hh, ll);
        if (r == 2) {
            kh[((size_t)j * S + s) * HD + lane] = hh;
            kl[((size_t)j * S + s) * HD + lane] = ll;
        } else {
            qh[((size_t)(j * 2 + r) * S + s) * HD + lane] = hh;
            ql[((size_t)(j * 2 + r) * S + s) * HD + lane] = ll;
        }
    }
}

// ---------------- scores = Q @ K^T * 0.125 (lower-triangle tiles), pre-split inputs ----------------
__global__ __launch_bounds__(256) void k_scores(const u16* __restrict__ qh, const u16* __restrict__ ql,
                                                const u16* __restrict__ kmh, const u16* __restrict__ kml,
                                                float* __restrict__ scores) {
    int kt = blockIdx.x, qt = blockIdx.y, h = blockIdx.z;
    if (kt > qt) return;
    size_t qoff = (size_t)h * S * HD;
    size_t koff = (size_t)(h >> 1) * S * HD;
    int lane = threadIdx.x & 63, wid = threadIdx.x >> 6;
    int wq = (wid >> 1) * 32, wk = (wid & 1) * 32;
    int q0 = qt * 64, k0 = kt * 64;
    f32x4 acc[2][2] = {};
#pragma unroll
    for (int ks = 0; ks < 2; ++ks) {
        bf16x8 ah[2], al[2], bh[2], bl[2];
#pragma unroll
        for (int mi = 0; mi < 2; ++mi) {
            size_t o = qoff + (size_t)(q0 + wq + mi * 16 + (lane & 15)) * HD + ks * 32 + (lane >> 4) * 8;
            ah[mi] = *(const bf16x8*)(qh + o);
            al[mi] = *(const bf16x8*)(ql + o);
        }
#pragma unroll
        for (int ni = 0; ni < 2; ++ni) {
            size_t o = koff + (size_t)(k0 + wk + ni * 16 + (lane & 15)) * HD + ks * 32 + (lane >> 4) * 8;
            bh[ni] = *(const bf16x8*)(kmh + o);
            bl[ni] = *(const bf16x8*)(kml + o);
        }
#pragma unroll
        for (int mi = 0; mi < 2; ++mi)
#pragma unroll
            for (int ni = 0; ni < 2; ++ni) {
                acc[mi][ni] = __builtin_amdgcn_mfma_f32_16x16x32_bf16(ah[mi], bh[ni], acc[mi][ni], 0, 0, 0);
                acc[mi][ni] = __builtin_amdgcn_mfma_f32_16x16x32_bf16(ah[mi], bl[ni], acc[mi][ni], 0, 0, 0);
                acc[mi][ni] = __builtin_amdgcn_mfma_f32_16x16x32_bf16(al[mi], bh[ni], acc[mi][ni], 0, 0, 0);
            }
    }
#pragma unroll
    for (int mi = 0; mi < 2; ++mi)
#pragma unroll
        for (int ni = 0; ni < 2; ++ni)
#pragma unroll
            for (int r = 0; r < 4; ++r) {
                int row = q0 + wq + mi * 16 + (lane >> 4) * 4 + r;
                int col = k0 + wk + ni * 16 + (lane & 15);
                scores[(size_t)h * S * S + (size_t)row * S + col] = acc[mi][ni][r] * 0.125f;
            }
}

// ---------------- causal softmax f32 -> P bf16 hi/lo (writes only up to diag tile) ----------------
__global__ __launch_bounds__(256) void k_softmax(const float* __restrict__ scores,
                                                 u16* __restrict__ Ph, u16* __restrict__ Pl) {
    int wid = threadIdx.x >> 6, lane = threadIdx.x & 63;
    int q = blockIdx.x * 4 + wid, h = blockIdx.y;
    const float* row = scores + (size_t)h * S * S + (size_t)q * S;
    size_t po = (size_t)h * S * S + (size_t)q * S;
    int L = q + 1;
    int wlim = ((q >> 6) + 1) * 64;
    float v[16];
    float mx = -1e30f;
#pragma unroll
    for (int i = 0; i < 16; ++i) {
        int idx = lane + i * 64;
        v[i] = (idx < L) ? row[idx] : -1e30f;
        mx = fmaxf(mx, v[i]);
    }
#pragma unroll
    for (int o = 32; o; o >>= 1) mx = fmaxf(mx, __shfl_xor(mx, o));
    float sum = 0.f;
#pragma unroll
    for (int i = 0; i < 16; ++i) {
        int idx = lane + i * 64;
        v[i] = (idx < L) ? __expf(v[i] - mx) : 0.f;
        sum += v[i];
    }
#pragma unroll
    for (int o = 32; o; o >>= 1) sum += __shfl_xor(sum, o);
    float inv = 1.f / sum;
#pragma unroll
    for (int i = 0; i < 16; ++i) {
        int idx = lane + i * 64;
        if (idx < wlim) {
            u16 hh, ll;
            split1(v[i] * inv, hh, ll);
            Ph[po + idx] = hh;
            Pl[po + idx] = ll;
        }
    }
}

// ---------------- O = P @ V (pre-split), writes ao bf16 hi/lo in (s, h*64+d) layout ----------------
__global__ __launch_bounds__(256) void k_pv(const u16* __restrict__ Ph, const u16* __restrict__ Pl,
                                            const u16* __restrict__ vmh, const u16* __restrict__ vml,
                                            u16* __restrict__ aoh, u16* __restrict__ aol) {
    int qt = blockIdx.x, h = blockIdx.y;
    size_t poff = (size_t)h * S * S;
    size_t voff = (size_t)(h >> 1) * S * HD;
    __shared__ u16 Vh[64][72];
    __shared__ u16 Vl[64][72];
    int tid = threadIdx.x, lane = tid & 63, wid = tid >> 6;
    int wq = (wid >> 1) * 32, wd = (wid & 1) * 32;
    int q0 = qt * 64;
    f32x4 acc[2][2] = {};
    int kmax = (qt + 1) * 64;
    for (int kc = 0; kc < kmax; kc += 64) {
#pragma unroll
        for (int i = 0; i < 16; ++i) {
            int idx = tid + i * 256;
            int kr = idx >> 6, d = idx & 63;
            Vh[d][kr] = vmh[voff + (size_t)(kc + kr) * HD + d];
            Vl[d][kr] = vml[voff + (size_t)(kc + kr) * HD + d];
        }
        __syncthreads();
#pragma unroll
        for (int ks = 0; ks < 2; ++ks) {
            bf16x8 ph[2], pl[2], vh[2], vl[2];
#pragma unroll
            for (int mi = 0; mi < 2; ++mi) {
                size_t o = poff + (size_t)(q0 + wq + mi * 16 + (lane & 15)) * S + kc + ks * 32 + (lane >> 4) * 8;
                ph[mi] = *(const bf16x8*)(Ph + o);
                pl[mi] = *(const bf16x8*)(Pl + o);
            }
#pragma unroll
            for (int ni = 0; ni < 2; ++ni) {
                vh[ni] = *(const bf16x8*)&Vh[wd + ni * 16 + (lane & 15)][ks * 32 + (lane >> 4) * 8];
                vl[ni] = *(const bf16x8*)&Vl[wd + ni * 16 + (lane & 15)][ks * 32 + (lane >> 4) * 8];
            }
#pragma unroll
            for (int mi = 0; mi < 2; ++mi)
#pragma unroll
                for (int ni = 0; ni < 2; ++ni) {
                    acc[mi][ni] = __builtin_amdgcn_mfma_f32_16x16x32_bf16(ph[mi], vh[ni], acc[mi][ni], 0, 0, 0);
                    acc[mi][ni] = __builtin_amdgcn_mfma_f32_16x16x32_bf16(ph[mi], vl[ni], acc[mi][ni], 0, 0, 0);
                    acc[mi][ni] = __builtin_amdgcn_mfma_f32_16x16x32_bf16(pl[mi], vh[ni], acc[mi][ni], 0, 0, 0);
                }
        }
        __syncthreads();
    }
#pragma unroll
    for (int mi = 0; mi < 2; ++mi)
#pragma unroll
        for (int ni = 0; ni < 2; ++ni)
#pragma unroll
            for (int r = 0; r < 4; ++r) {
                int row = q0 + wq + mi * 16 + (lane >> 4) * 4 + r;
                int col = wd + ni * 16 + (lane & 15);
                u16 hh, ll; split1(acc[mi][ni][r], hh, ll);
                aoh[(size_t)row * MDIM + h * HD + col] = hh;
                aol[(size_t)row * MDIM + h * HD + col] = ll;
            }
}

// ---------------- fused RMS norm 2 + router logits + top-8 ----------------
__global__ __launch_bounds__(256) void k_rms2_router(const float* __restrict__ h,
                                                     const float* __restrict__ w,
                                                     const float* __restrict__ gw,
                                                     u16* __restrict__ h2b,
                                                     int* __restrict__ topi,
                                                     float* __restrict__ wts) {
    __shared__ float xr[1024];
    __shared__ float part[4][64];
    __shared__ float red[4];
    int s = blockIdx.x, tid = threadIdx.x;
    const float* row = h + (size_t)s * MDIM;
    float v[4]; float ss = 0.f;
#pragma unroll
    for (int i = 0; i < 4; ++i) { v[i] = row[tid + i * 256]; ss += v[i] * v[i]; }
#pragma unroll
    for (int of = 32; of; of >>= 1) ss += __shfl_xor(ss, of);
    if ((tid & 63) == 0) red[tid >> 6] = ss;
    __syncthreads();
    float tot = red[0] + red[1] + red[2] + red[3];
    float sc = rsqrtf(tot * (1.f / MDIM) + 1e-6f);
#pragma unroll
    for (int i = 0; i < 4; ++i) {
        int c = tid + i * 256;
        float ov = v[i] * sc * w[c];
        xr[c] = ov;
        h2b[(size_t)s * MDIM + c] = f2bf(ov);
    }
    __syncthreads();
    int e = tid & 63, qq = tid >> 6;
    float acc = 0.f;
    for (int i = 0; i < 256; ++i) acc += xr[qq * 256 + i] * gw[(size_t)(qq * 256 + i) * NE + e];
    part[qq][e] = acc;
    __syncthreads();
    if (tid < 64) {
        int lane = tid;
        float lg = part[0][lane] + part[1][lane] + part[2][lane] + part[3][lane];
        float mx = lg;
#pragma unroll
        for (int o = 32; o; o >>= 1) mx = fmaxf(mx, __shfl_xor(mx, o));
        float ex = __expf(lg - mx);
        float sum = ex;
#pragma unroll
        for (int o = 32; o; o >>= 1) sum += __shfl_xor(sum, o);
        float g = ex / sum;
        float cur = g;
        float tv[TOPK]; int ti[TOPK];
        float tsum = 0.f;
#pragma unroll
        for (int k = 0; k < TOPK; ++k) {
            float vv = cur; int ii = lane;
#pragma unroll
            for (int o = 32; o; o >>= 1) {
                float vo = __shfl_xor(vv, o);
                int io = __shfl_xor(ii, o);
                if (vo > vv || (vo == vv && io < ii)) { vv = vo; ii = io; }
            }
            tv[k] = vv; ti[k] = ii; tsum += vv;
            if (lane == ii) cur = -1.f;
        }
        float gs = fmaxf(tsum, 1.1920929e-07f);
        if (lane == 0) {
#pragma unroll
            for (int k = 0; k < TOPK; ++k) {
                topi[s * TOPK + k] = ti[k];
                wts[s * TOPK + k] = tv[k] / gs;
            }
        }
    }
}

// ---------------- parallel rank-major priority / capacity assignment ----------------
__global__ __launch_bounds__(512) void k_slots(const int* __restrict__ topi, int* __restrict__ slots,
                                               int* __restrict__ counts, int* __restrict__ etok) {
    __shared__ int tl[S * TOPK];
    __shared__ int cnt[TOPK][NE];
    __shared__ int base[TOPK][NE];
    int tid = threadIdx.x;
    for (int i = tid; i < S * TOPK; i += 512) tl[i] = topi[i];
    ((int*)cnt)[tid] = 0;   // 512 == TOPK*NE
    __syncthreads();
    for (int i = tid; i < S * TOPK; i += 512)
        atomicAdd(&cnt[i & 7][tl[i]], 1);
    __syncthreads();
    if (tid < NE) {
        int acc = 0;
#pragma unroll
        for (int k = 0; k < TOPK; ++k) { base[k][tid] = acc; acc += cnt[k][tid]; }
        counts[tid] = acc < CAP ? acc : CAP;
    }
    __syncthreads();
    int k = tid >> 6, e = tid & 63;
    int rank = base[k][e];
    for (int s = 0; s < S; ++s) {
        if (tl[s * TOPK + k] == e) {
            if (rank < CAP) { slots[s * TOPK + k] = rank; etok[e * CAP + rank] = s; }
            else slots[s * TOPK + k] = -1;
            rank++;
        }
    }
}

// ---------------- final combine: out = h + shared + sum_k w_k * eo[e_k, slot_k] ----------------
__global__ __launch_bounds__(256) void k_combine(const float* __restrict__ h,
                                                 const u16* __restrict__ sh,
                                                 const u16* __restrict__ eo,
                                                 const int* __restrict__ topi,
                                                 const int* __restrict__ slots,
                                                 const float* __restrict__ wts,
                                                 float* __restrict__ out) {
    int s = blockIdx.x, t = threadIdx.x;
    float w[TOPK]; int off[TOPK];
#pragma unroll
    for (int k = 0; k < TOPK; ++k) {
        int sl = slots[s * TOPK + k];
        int ee = topi[s * TOPK + k];
        w[k] = wts[s * TOPK + k];
        off[k] = (sl >= 0) ? ee * CAP + sl : -1;
    }
#pragma unroll
    for (int i = 0; i < 4; ++i) {
        int col = t + i * 256;
        float acc = h[(size_t)s * MDIM + col] + bf2f(sh[(size_t)s * MDIM + col]);
#pragma unroll
        for (int k = 0; k < TOPK; ++k)
            if (off[k] >= 0) acc += w[k] * bf2f(eo[(size_t)off[k] * MDIM + col]);
        out[(size_t)s * MDIM + col] = acc;
    }
}

extern "C" void kernel_launch(void* const* d_in, const int* in_sizes, int n_in,
                              void* d_out, int out_size, void* d_ws, size_t ws_size,
                              hipStream_t stream) {
    (void)in_sizes; (void)n_in; (void)out_size; (void)ws_size;
    const float* hidden = (const float*)d_in[0];
    const float* cosb   = (const float*)d_in[1];
    const float* sinb   = (const float*)d_in[2];
    const float* ln1_w  = (const float*)d_in[3];
    const float* ln2_w  = (const float*)d_in[4];
    const float* qkv_w  = (const float*)d_in[5];
    const float* o_w    = (const float*)d_in[6];
    const float* qn_w   = (const float*)d_in[7];
    const float* kn_w   = (const float*)d_in[8];
    const float* sgu_w  = (const float*)d_in[9];
    const float* sdn_w  = (const float*)d_in[10];
    const float* gate_w = (const float*)d_in[11];
    const float* egu_w  = (const float*)d_in[12];
    const float* edn_w  = (const float*)d_in[13];
    float* out = (float*)d_out;

    char* ws = (char*)d_ws;
    size_t off = 0;
    auto alloc = [&](size_t bytes) -> void* {
        void* p = ws + off;
        off = (off + bytes + 255) & ~(size_t)255;
        return p;
    };
    u16*   hn_hi   = (u16*)  alloc((size_t)S * MDIM * 2);
    u16*   hn_lo   = (u16*)  alloc((size_t)S * MDIM * 2);
    float* qkvb    = (float*)alloc((size_t)S * 2048 * 4);
    u16*   qhb     = (u16*)  alloc((size_t)NH * S * HD * 2);
    u16*   qlb     = (u16*)  alloc((size_t)NH * S * HD * 2);
    u16*   khb     = (u16*)  alloc((size_t)NKV * S * HD * 2);
    u16*   klb     = (u16*)  alloc((size_t)NKV * S * HD * 2);
    u16*   vhb     = (u16*)  alloc((size_t)NKV * S * HD * 2);
    u16*   vlb     = (u16*)  alloc((size_t)NKV * S * HD * 2);
    float* scores  = (float*)alloc((size_t)NH * S * S * 4);
    u16*   Phb     = (u16*)  alloc((size_t)NH * S * S * 2);
    u16*   Plb     = (u16*)  alloc((size_t)NH * S * S * 2);
    u16*   ao_hi   = (u16*)  alloc((size_t)S * MDIM * 2);
    u16*   ao_lo   = (u16*)  alloc((size_t)S * MDIM * 2);
    float* hbuf    = (float*)alloc((size_t)S * MDIM * 4);
    u16*   h2b     = (u16*)  alloc((size_t)S * MDIM * 2);
    u16*   gatedS  = (u16*)  alloc((size_t)S * FF * 2);
    u16*   sharedO = (u16*)  alloc((size_t)S * MDIM * 2);
    int*   topi    = (int*)  alloc((size_t)S * TOPK * 4);
    float* wts     = (float*)alloc((size_t)S * TOPK * 4);
    int*   slots   = (int*)  alloc((size_t)S * TOPK * 4);
    int*   counts  = (int*)  alloc((size_t)NE * 4);
    int*   etok    = (int*)  alloc((size_t)NE * CAP * 4);
    u16*   egated  = (u16*)  alloc((size_t)NE * CAP * FF * 2);
    u16*   eo      = (u16*)  alloc((size_t)NE * CAP * MDIM * 2);

    // 1. RMS norm 1 -> hn hi/lo
    k_rms1<<<dim3(S), 256, 0, stream>>>(hidden, ln1_w, hn_hi, hn_lo);
    // 2. QKV projection (3-term split, pipelined, gload_lds A)
    k_gemm_split<0><<<dim3(2048 / 64, S / 64), 256, 0, stream>>>(
        hn_hi, hn_lo, MDIM, qkv_w, 2048, qkvb, 2048, nullptr, S, MDIM);
    // 3. unpack + RoPE + q/k RMS -> pre-split bf16
    k_rope<<<dim3(S * NKV / 4), 256, 0, stream>>>(qkvb, cosb, sinb, qn_w, kn_w,
                                                  qhb, qlb, khb, klb, vhb, vlb);
    // 4. scores (lower triangle, 3-term)
    k_scores<<<dim3(16, 16, NH), 256, 0, stream>>>(qhb, qlb, khb, klb, scores);
    // 5. causal softmax -> P hi/lo
    k_softmax<<<dim3(S / 4, NH), 256, 0, stream>>>(scores, Phb, Plb);
    // 6. P @ V -> ao hi/lo (3-term)
    k_pv<<<dim3(16, NH), 256, 0, stream>>>(Phb, Plb, vhb, vlb, ao_hi, ao_lo);
    // 7. O projection + residual -> h f32 (3-term)
    k_gemm_split<1><<<dim3(MDIM / 64, S / 64), 256, 0, stream>>>(
        ao_hi, ao_lo, MDIM, o_w, MDIM, hbuf, MDIM, hidden, S, MDIM);
    // 8. fused RMS norm 2 + router logits + top-8
    k_rms2_router<<<dim3(S), 256, 0, stream>>>(hbuf, ln2_w, gate_w, h2b, topi, wts);
    // 9. capacity / slot assignment
    k_slots<<<dim3(1), 512, 0, stream>>>(topi, slots, counts, etok);
    // 10. expert-up + shared-up merged (swiglu) -> egated / gatedS (bf16)
    k_gemm_bf<160, 64, true><<<dim3(FF / 64, 2, NE + 4), 256, 0, stream>>>(
        h2b, MDIM, 0, egu_w, (long)MDIM * 2 * FF, 2 * FF,
        egated, FF, (long)CAP * FF, MDIM, FF, counts, etok,
        h2b, sgu_w, gatedS, S);
    // 11. expert-down + shared-down merged -> eo / sharedO (bf16)
    k_gemm_bf<160, 128, false><<<dim3(MDIM / 128, 2, NE + 4), 256, 0, stream>>>(
        egated, FF, (long)CAP * FF, edn_w, (long)FF * MDIM, MDIM,
        eo, MDIM, (long)CAP * MDIM, FF, 0, counts, nullptr,
        gatedS, sdn_w, sharedO, S);
    // 12. combine: out = h + shared + moe
    k_combine<<<dim3(S), 256, 0, stream>>>(hbuf, sharedO, eo, topi, slots, wts, out);
}

// Round 7
// 902.720 us; speedup vs baseline: 2.7841x; 1.1442x over previous
//
#include <hip/hip_runtime.h>

#define S 1024
#define MDIM 1024
#define NH 16
#define HD 64
#define NKV 8
#define FF 3072
#define NE 64
#define TOPK 8
#define CAP 256

typedef unsigned short u16;
typedef __attribute__((ext_vector_type(8))) short bf16x8;
typedef __attribute__((ext_vector_type(4))) float f32x4;

__device__ __forceinline__ u16 f2bf(float f) {
    union { float f; unsigned u; } x; x.f = f;
    unsigned r = x.u + 0x7FFFu + ((x.u >> 16) & 1u);
    return (u16)(r >> 16);
}
__device__ __forceinline__ float bf2f(u16 b) {
    union { unsigned u; float f; } x; x.u = ((unsigned)b) << 16;
    return x.f;
}
__device__ __forceinline__ void split1(float x, u16& h, u16& l) {
    h = f2bf(x);
    l = f2bf(x - bf2f(h));
}
// swizzled column (u16 units) for k-octet G in row `row` of a [R][40] B-tile
__device__ __forceinline__ int swzcol(int row, int G) { return 8 * (G ^ ((row >> 3) & 3)); }

// 16B global->LDS DMA (dest = wave-uniform base + lane*16)
__device__ __forceinline__ void gl_lds16(const u16* g, u16* l) {
    __builtin_amdgcn_global_load_lds(
        (const __attribute__((address_space(1))) unsigned int*)g,
        (__attribute__((address_space(3))) unsigned int*)l, 16, 0, 0);
}

// ---------------- RMS norm 1: writes pre-split bf16 hi/lo ----------------
__global__ __launch_bounds__(256) void k_rms1(const float* __restrict__ x,
                                              const float* __restrict__ w,
                                              u16* __restrict__ ohi,
                                              u16* __restrict__ olo) {
    int s = blockIdx.x;
    const float* row = x + (size_t)s * MDIM;
    float v[4]; float ss = 0.f;
#pragma unroll
    for (int i = 0; i < 4; ++i) { v[i] = row[threadIdx.x + i * 256]; ss += v[i] * v[i]; }
#pragma unroll
    for (int of = 32; of; of >>= 1) ss += __shfl_xor(ss, of);
    __shared__ float red[4];
    int wid = threadIdx.x >> 6;
    if ((threadIdx.x & 63) == 0) red[wid] = ss;
    __syncthreads();
    float tot = red[0] + red[1] + red[2] + red[3];
    float sc = rsqrtf(tot * (1.f / MDIM) + 1e-6f);
#pragma unroll
    for (int i = 0; i < 4; ++i) {
        int c = threadIdx.x + i * 256;
        float ov = v[i] * sc * w[c];
        u16 hh, ll; split1(ov, hh, ll);
        ohi[(size_t)s * MDIM + c] = hh;
        olo[(size_t)s * MDIM + c] = ll;
    }
}

// ---------------- 3-term split GEMM, pipelined + gload_lds A ----------------
// EPI: 0 = f32 out, 1 = f32 out + resid
template <int EPI>
__global__ __launch_bounds__(256) void k_gemm_split(
    const u16* __restrict__ Ahi, const u16* __restrict__ Alo, int lda,
    const float* __restrict__ B, int ldb,
    float* __restrict__ C, int ldc,
    const float* __restrict__ resid, int M, int K) {
    int m0 = blockIdx.y * 64;
    int n0 = blockIdx.x * 64;
    __shared__ u16 Ah[2][64][32];
    __shared__ u16 Al[2][64][32];
    __shared__ u16 Bh[2][64][40];
    __shared__ u16 Bl[2][64][40];
    int tid = threadIdx.x, lane = tid & 63, wid = tid >> 6;
    int wm = (wid >> 1) * 32, wn = (wid & 1) * 32;
    f32x4 acc[2][2] = {};

    int rt = wid * 16 + (lane >> 2);
    int gsrc = (lane & 3) ^ ((lane >> 4) & 3);
    const u16* ahb = Ahi + (size_t)(m0 + rt) * lda + gsrc * 8;
    const u16* alb = Alo + (size_t)(m0 + rt) * lda + gsrc * 8;

    int nB = tid & 63, kbB = tid >> 6;
    int colB = swzcol(nB, kbB);
    float rb[8];
    auto loadB = [&](int k0) {
        const float* bp = B + (size_t)(k0 + kbB * 8) * ldb + n0 + nB;
#pragma unroll
        for (int i = 0; i < 8; ++i) rb[i] = bp[(size_t)i * ldb];
    };
    auto stageA = [&](int b, int k0) {
        gl_lds16(ahb + k0, &Ah[b][wid * 16][0]);
        gl_lds16(alb + k0, &Al[b][wid * 16][0]);
    };
    auto writeB = [&](int b) {
        bf16x8 hh, ll;
#pragma unroll
        for (int i = 0; i < 8; ++i) { u16 h, l; split1(rb[i], h, l); hh[i] = (short)h; ll[i] = (short)l; }
        *(bf16x8*)&Bh[b][nB][colB] = hh;
        *(bf16x8*)&Bl[b][nB][colB] = ll;
    };

    loadB(0); stageA(0, 0); writeB(0);
    __syncthreads();
    int NT = K / 32;
    for (int t = 0; t < NT; ++t) {
        int c = t & 1;
        if (t + 1 < NT) { loadB((t + 1) * 32); stageA(1 - c, (t + 1) * 32); }
        bf16x8 ah[2], al[2], bh[2], bl[2];
#pragma unroll
        for (int mi = 0; mi < 2; ++mi) {
            int r = wm + mi * 16 + (lane & 15);
            int cA = 8 * ((lane >> 4) ^ ((r >> 2) & 3));
            ah[mi] = *(const bf16x8*)&Ah[c][r][cA];
            al[mi] = *(const bf16x8*)&Al[c][r][cA];
        }
#pragma unroll
        for (int ni = 0; ni < 2; ++ni) {
            int r = wn + ni * 16 + (lane & 15);
            int cc = swzcol(r, lane >> 4);
            bh[ni] = *(const bf16x8*)&Bh[c][r][cc];
            bl[ni] = *(const bf16x8*)&Bl[c][r][cc];
        }
#pragma unroll
        for (int mi = 0; mi < 2; ++mi)
#pragma unroll
            for (int ni = 0; ni < 2; ++ni) {
                acc[mi][ni] = __builtin_amdgcn_mfma_f32_16x16x32_bf16(ah[mi], bh[ni], acc[mi][ni], 0, 0, 0);
                acc[mi][ni] = __builtin_amdgcn_mfma_f32_16x16x32_bf16(ah[mi], bl[ni], acc[mi][ni], 0, 0, 0);
                acc[mi][ni] = __builtin_amdgcn_mfma_f32_16x16x32_bf16(al[mi], bh[ni], acc[mi][ni], 0, 0, 0);
            }
        if (t + 1 < NT) { writeB(1 - c); __syncthreads(); }
    }
#pragma unroll
    for (int mi = 0; mi < 2; ++mi)
#pragma unroll
        for (int ni = 0; ni < 2; ++ni)
#pragma unroll
            for (int r = 0; r < 4; ++r) {
                int row = m0 + wm + mi * 16 + (lane >> 4) * 4 + r;
                int col = n0 + wn + ni * 16 + (lane & 15);
                float v = acc[mi][ni][r];
                if constexpr (EPI == 1) v += resid[(size_t)row * ldc + col];
                C[(size_t)row * ldc + col] = v;
            }
}

// ---------------- 1-term bf16 GEMM, pipelined + gload_lds A; merged expert+shared ----------------
// XCD1D: 1D grid with XCD-affinity mapping (expert e's n-tiles share id%8 -> same XCD L2)
template <int TM, int TN, bool SWIGLU, bool XCD1D>
__global__ __launch_bounds__(256) void k_gemm_bf(
    const u16* __restrict__ A, int lda, long sAe,
    const float* __restrict__ B, long sBe, int ldb,
    u16* __restrict__ C, int ldc, long sCe,
    int K, int pairOff,
    const int* __restrict__ counts, const int* __restrict__ rowidx,
    const u16* __restrict__ Ash, const float* __restrict__ Bsh,
    u16* __restrict__ Csh, int Msh) {
    int z, byy, bxx;
    if constexpr (XCD1D) {
        int id = blockIdx.x;
        if (id < 1024) { byy = id >> 9; int t = id & 511; z = ((t >> 6) << 3) | (t & 7); bxx = (t >> 3) & 7; }
        else { int ms = id - 1024; z = NE + (ms >> 4); byy = (ms >> 3) & 1; bxx = ms & 7; }
    } else {
        z = blockIdx.z; byy = blockIdx.y; bxx = blockIdx.x;
    }
    int tid = threadIdx.x, lane = tid & 63, wid = tid >> 6;
    int M, m0;
    const int* ridx = nullptr;
    if (z >= NE) {
        int mslot = (z - NE) * 2 + byy;
        m0 = mslot * TM;
        M = Msh;
        A = Ash; B = Bsh; C = Csh;
        if (m0 >= M) return;
    } else {
        M = counts[z];
        m0 = byy * TM;
        if (m0 >= M) return;
        A += (size_t)z * sAe;
        B += (size_t)z * sBe;
        C += (size_t)z * sCe;
        if (rowidx) ridx = rowidx + z * CAP;
    }
    int n0 = bxx * TN;

    __shared__ u16 As[2][TM][32];
    __shared__ u16 Bs[2][TN][40];
    __shared__ u16 B2s[2][SWIGLU ? TN : 1][40];

    constexpr int MF = TM / 32;
    constexpr int NI = TN / 32;
    int wm = (wid >> 1) * (TM / 2), wn = (wid & 1) * (TN / 2);

    f32x4 acc[MF][NI] = {};
    f32x4 acc2[SWIGLU ? MF : 1][NI] = {};

    constexpr int NCH = TM / 16;
    constexpr int CPW = (NCH + 3) / 4;
    int arow_in = lane >> 2;
    int gsrc = (lane & 3) ^ ((lane >> 4) & 3);
    const u16* abase[CPW];
#pragma unroll
    for (int i = 0; i < CPW; ++i) {
        int ch = wid + i * 4;
        const u16* p = A;
        if (ch < NCH) {
            int rti = ch * 16 + arow_in;
            int gm = m0 + rti;
            long grow = (gm < M) ? (ridx ? (long)ridx[gm] : (long)gm) : 0;
            p = A + grow * (size_t)lda + gsrc * 8;
        }
        abase[i] = p;
    }
    auto stageA = [&](int b, int k0) {
#pragma unroll
        for (int i = 0; i < CPW; ++i) {
            int ch = wid + i * 4;
            if (ch < NCH) gl_lds16(abase[i] + k0, &As[b][ch * 16][0]);
        }
    };

    constexpr int NKG = 256 / TN;
    constexpr int OPT = 4 / NKG;
    int nB = tid % TN, kgB = tid / TN;
    float rb[OPT][8], rg[SWIGLU ? OPT : 1][8];
    auto loadB = [&](int k0) {
        const float* bp = B + (size_t)(k0 + kgB * OPT * 8) * ldb + n0 + nB;
#pragma unroll
        for (int j = 0; j < OPT; ++j)
#pragma unroll
            for (int i = 0; i < 8; ++i) {
                rb[j][i] = bp[(size_t)(j * 8 + i) * ldb];
                if constexpr (SWIGLU) rg[j][i] = bp[(size_t)(j * 8 + i) * ldb + pairOff];
            }
    };
    auto writeB = [&](int b) {
#pragma unroll
        for (int j = 0; j < OPT; ++j) {
            int col = swzcol(nB, kgB * OPT + j);
            bf16x8 v;
#pragma unroll
            for (int i = 0; i < 8; ++i) v[i] = (short)f2bf(rb[j][i]);
            *(bf16x8*)&Bs[b][nB][col] = v;
            if constexpr (SWIGLU) {
                bf16x8 g;
#pragma unroll
                for (int i = 0; i < 8; ++i) g[i] = (short)f2bf(rg[j][i]);
                *(bf16x8*)&B2s[b][nB][col] = g;
            }
        }
    };

    loadB(0); stageA(0, 0); writeB(0);
    __syncthreads();
    int NT = K / 32;
    for (int t = 0; t < NT; ++t) {
        int c = t & 1;
        if (t + 1 < NT) { loadB((t + 1) * 32); stageA(1 - c, (t + 1) * 32); }
        bf16x8 af[MF], bfr[NI], gfr[SWIGLU ? NI : 1];
#pragma unroll
        for (int mi = 0; mi < MF; ++mi) {
            int r = wm + mi * 16 + (lane & 15);
            int cA = 8 * ((lane >> 4) ^ ((r >> 2) & 3));
            af[mi] = *(const bf16x8*)&As[c][r][cA];
        }
#pragma unroll
        for (int ni = 0; ni < NI; ++ni) {
            int r = wn + ni * 16 + (lane & 15);
            int cB = swzcol(r, lane >> 4);
            bfr[ni] = *(const bf16x8*)&Bs[c][r][cB];
            if constexpr (SWIGLU) gfr[ni] = *(const bf16x8*)&B2s[c][r][cB];
        }
#pragma unroll
        for (int mi = 0; mi < MF; ++mi)
#pragma unroll
            for (int ni = 0; ni < NI; ++ni) {
                acc[mi][ni] = __builtin_amdgcn_mfma_f32_16x16x32_bf16(af[mi], bfr[ni], acc[mi][ni], 0, 0, 0);
                if constexpr (SWIGLU)
                    acc2[mi][ni] = __builtin_amdgcn_mfma_f32_16x16x32_bf16(af[mi], gfr[ni], acc2[mi][ni], 0, 0, 0);
            }
        if (t + 1 < NT) { writeB(1 - c); __syncthreads(); }
    }
#pragma unroll
    for (int mi = 0; mi < MF; ++mi)
#pragma unroll
        for (int ni = 0; ni < NI; ++ni)
#pragma unroll
            for (int r = 0; r < 4; ++r) {
                int row = m0 + wm + mi * 16 + (lane >> 4) * 4 + r;
                int col = n0 + wn + ni * 16 + (lane & 15);
                if (row >= M) continue;
                float x1 = acc[mi][ni][r];
                if constexpr (SWIGLU) {
                    float x2 = acc2[mi][ni][r];
                    x1 = x1 * (x2 / (1.f + __expf(-x2)));
                }
                C[(size_t)row * ldc + col] = f2bf(x1);
            }
}

// ---------------- unpack QKV + RoPE + q/k RMS norm -> pre-split bf16 hi/lo ----------------
__global__ __launch_bounds__(256) void k_rope(const float* __restrict__ qkv,
                                              const float* __restrict__ cosb,
                                              const float* __restrict__ sinb,
                                              const float* __restrict__ qn_w,
                                              const float* __restrict__ kn_w,
                                              u16* __restrict__ qh, u16* __restrict__ ql,
                                              u16* __restrict__ kh, u16* __restrict__ kl,
                                              u16* __restrict__ vh, u16* __restrict__ vl) {
    int wid = threadIdx.x >> 6, lane = threadIdx.x & 63;
    int idx = blockIdx.x * 4 + wid;   // 0..8191
    int s = idx >> 3, j = idx & 7;
    const float* base = qkv + (size_t)s * 2048 + j * 256;
    float c = cosb[s * HD + lane], sn = sinb[s * HD + lane];
    u16 hh, ll;
    split1(base[192 + lane], hh, ll);
    vh[((size_t)j * S + s) * HD + lane] = hh;
    vl[((size_t)j * S + s) * HD + lane] = ll;
#pragma unroll
    for (int r = 0; r < 3; ++r) {
        float x = base[r * 64 + lane];
        float xp = __shfl_xor(x, 32);
        float rot = (lane < 32) ? -xp : xp;
        float y = x * c + rot * sn;
        float ss = y * y;
#pragma unroll
        for (int o = 32; o; o >>= 1) ss += __shfl_xor(ss, o);
        float scale = rsqrtf(ss * (1.f / 64.f) + 1e-6f);
        float outv = y * scale * ((r == 2) ? kn_w[lane] : qn_w[lane]);
        split1(outv, hh, ll);
        if (r == 2) {
            kh[((size_t)j * S + s) * HD + lane] = hh;
            kl[((size_t)j * S + s) * HD + lane] = ll;
        } else {
            qh[((size_t)(j * 2 + r) * S + s) * HD + lane] = hh;
            ql[((size_t)(j * 2 + r) * S + s) * HD + lane] = ll;
        }
    }
}

// ---------------- fused flash attention: per (h, 64-q tile), online softmax ----------------
__global__ __launch_bounds__(256) void k_attn(const u16* __restrict__ qh, const u16* __restrict__ ql,
                                              const u16* __restrict__ kmh, const u16* __restrict__ kml,
                                              const u16* __restrict__ vmh, const u16* __restrict__ vml,
                                              u16* __restrict__ aoh, u16* __restrict__ aol) {
    int qt = 15 - blockIdx.x;       // big tiles first
    int h = blockIdx.y;
    int q0 = qt * 64;
    size_t qoff = (size_t)h * S * HD;
    size_t koff = (size_t)(h >> 1) * S * HD;
    size_t voff = koff;

    __shared__ u16 Vh[64][72];
    __shared__ u16 Vl[64][72];
    __shared__ u16 Ph_l[4][16][72];
    __shared__ u16 Pl_l[4][16][72];

    int tid = threadIdx.x, lane = tid & 63, w = tid >> 6;
    int rgrp = lane >> 4;           // 0..3
    int l16 = lane & 15;

    // hoisted Q fragments (16 q-rows for this wave)
    bf16x8 qfh[2], qfl[2];
#pragma unroll
    for (int ks = 0; ks < 2; ++ks) {
        size_t o = qoff + (size_t)(q0 + w * 16 + l16) * HD + ks * 32 + rgrp * 8;
        qfh[ks] = *(const bf16x8*)(qh + o);
        qfl[ks] = *(const bf16x8*)(ql + o);
    }

    float m_[4], l_[4];
    f32x4 o_[4] = {};
#pragma unroll
    for (int r = 0; r < 4; ++r) { m_[r] = -1e30f; l_[r] = 0.f; }

    for (int kt = 0; kt <= qt; ++kt) {
        int kc = kt * 64;
        // stage V tile transposed (cooperative)
#pragma unroll
        for (int i = 0; i < 16; ++i) {
            int idx = tid + i * 256;
            int kr = idx >> 6, d = idx & 63;
            Vh[d][kr] = vmh[voff + (size_t)(kc + kr) * HD + d];
            Vl[d][kr] = vml[voff + (size_t)(kc + kr) * HD + d];
        }
        __syncthreads();

        // QK^T (3-term) -> sacc[ni] (16 q x 64 k per wave)
        f32x4 sacc[4] = {};
#pragma unroll
        for (int ks = 0; ks < 2; ++ks) {
            bf16x8 bh[4], bl[4];
#pragma unroll
            for (int ni = 0; ni < 4; ++ni) {
                size_t o = koff + (size_t)(kc + ni * 16 + l16) * HD + ks * 32 + rgrp * 8;
                bh[ni] = *(const bf16x8*)(kmh + o);
                bl[ni] = *(const bf16x8*)(kml + o);
            }
#pragma unroll
            for (int ni = 0; ni < 4; ++ni) {
                sacc[ni] = __builtin_amdgcn_mfma_f32_16x16x32_bf16(qfh[ks], bh[ni], sacc[ni], 0, 0, 0);
                sacc[ni] = __builtin_amdgcn_mfma_f32_16x16x32_bf16(qfh[ks], bl[ni], sacc[ni], 0, 0, 0);
                sacc[ni] = __builtin_amdgcn_mfma_f32_16x16x32_bf16(qfl[ks], bh[ni], sacc[ni], 0, 0, 0);
            }
        }
        // scale + causal mask
#pragma unroll
        for (int ni = 0; ni < 4; ++ni)
#pragma unroll
            for (int r = 0; r < 4; ++r) {
                int qrow = q0 + w * 16 + rgrp * 4 + r;
                int col = kc + ni * 16 + l16;
                float sv = sacc[ni][r] * 0.125f;
                sacc[ni][r] = (col > qrow) ? -1e30f : sv;
            }
        // row max (across 4 ni + 16 lanes of the quarter-group)
        float pm[4], mnew[4], sf[4], ps[4];
#pragma unroll
        for (int r = 0; r < 4; ++r) {
            float mx = fmaxf(fmaxf(sacc[0][r], sacc[1][r]), fmaxf(sacc[2][r], sacc[3][r]));
#pragma unroll
            for (int off = 1; off < 16; off <<= 1) mx = fmaxf(mx, __shfl_xor(mx, off));
            pm[r] = mx;
            mnew[r] = fmaxf(m_[r], pm[r]);
            sf[r] = __expf(m_[r] - mnew[r]);
            m_[r] = mnew[r];
            ps[r] = 0.f;
        }
        // P = exp(s - mnew); rowsum; write P hi/lo to per-wave LDS
#pragma unroll
        for (int ni = 0; ni < 4; ++ni)
#pragma unroll
            for (int r = 0; r < 4; ++r) {
                float p = __expf(sacc[ni][r] - mnew[r]);
                ps[r] += p;
                u16 hh, ll; split1(p, hh, ll);
                Ph_l[w][rgrp * 4 + r][ni * 16 + l16] = hh;
                Pl_l[w][rgrp * 4 + r][ni * 16 + l16] = ll;
            }
#pragma unroll
        for (int r = 0; r < 4; ++r) {
            float s_ = ps[r];
#pragma unroll
            for (int off = 1; off < 16; off <<= 1) s_ += __shfl_xor(s_, off);
            l_[r] = l_[r] * sf[r] + s_;
        }
        // rescale O
#pragma unroll
        for (int ni = 0; ni < 4; ++ni)
#pragma unroll
            for (int r = 0; r < 4; ++r) o_[ni][r] *= sf[r];
        // PV (3-term): A = P from LDS, B = V^T from LDS
#pragma unroll
        for (int ks2 = 0; ks2 < 2; ++ks2) {
            bf16x8 pah = *(const bf16x8*)&Ph_l[w][l16][ks2 * 32 + rgrp * 8];
            bf16x8 pal = *(const bf16x8*)&Pl_l[w][l16][ks2 * 32 + rgrp * 8];
            bf16x8 vbh[4], vbl[4];
#pragma unroll
            for (int ni = 0; ni < 4; ++ni) {
                vbh[ni] = *(const bf16x8*)&Vh[ni * 16 + l16][ks2 * 32 + rgrp * 8];
                vbl[ni] = *(const bf16x8*)&Vl[ni * 16 + l16][ks2 * 32 + rgrp * 8];
            }
#pragma unroll
            for (int ni = 0; ni < 4; ++ni) {
                o_[ni] = __builtin_amdgcn_mfma_f32_16x16x32_bf16(pah, vbh[ni], o_[ni], 0, 0, 0);
                o_[ni] = __builtin_amdgcn_mfma_f32_16x16x32_bf16(pah, vbl[ni], o_[ni], 0, 0, 0);
                o_[ni] = __builtin_amdgcn_mfma_f32_16x16x32_bf16(pal, vbh[ni], o_[ni], 0, 0, 0);
            }
        }
        __syncthreads();
    }
    // epilogue: normalize + split + store
#pragma unroll
    for (int r = 0; r < 4; ++r) {
        float inv = 1.f / l_[r];
        int row = q0 + w * 16 + rgrp * 4 + r;
#pragma unroll
        for (int ni = 0; ni < 4; ++ni) {
            float val = o_[ni][r] * inv;
            u16 hh, ll; split1(val, hh, ll);
            size_t o = (size_t)row * MDIM + h * HD + ni * 16 + l16;
            aoh[o] = hh;
            aol[o] = ll;
        }
    }
}

// ---------------- fused RMS norm 2 + router logits + top-8 ----------------
__global__ __launch_bounds__(256) void k_rms2_router(const float* __restrict__ h,
                                                     const float* __restrict__ w,
                                                     const float* __restrict__ gw,
                                                     u16* __restrict__ h2b,
                                                     int* __restrict__ topi,
                                                     float* __restrict__ wts) {
    __shared__ float xr[1024];
    __shared__ float part[4][64];
    __shared__ float red[4];
    int s = blockIdx.x, tid = threadIdx.x;
    const float* row = h + (size_t)s * MDIM;
    float v[4]; float ss = 0.f;
#pragma unroll
    for (int i = 0; i < 4; ++i) { v[i] = row[tid + i * 256]; ss += v[i] * v[i]; }
#pragma unroll
    for (int of = 32; of; of >>= 1) ss += __shfl_xor(ss, of);
    if ((tid & 63) == 0) red[tid >> 6] = ss;
    __syncthreads();
    float tot = red[0] + red[1] + red[2] + red[3];
    float sc = rsqrtf(tot * (1.f / MDIM) + 1e-6f);
#pragma unroll
    for (int i = 0; i < 4; ++i) {
        int c = tid + i * 256;
        float ov = v[i] * sc * w[c];
        xr[c] = ov;
        h2b[(size_t)s * MDIM + c] = f2bf(ov);
    }
    __syncthreads();
    int e = tid & 63, qq = tid >> 6;
    float acc = 0.f;
    for (int i = 0; i < 256; ++i) acc += xr[qq * 256 + i] * gw[(size_t)(qq * 256 + i) * NE + e];
    part[qq][e] = acc;
    __syncthreads();
    if (tid < 64) {
        int lane = tid;
        float lg = part[0][lane] + part[1][lane] + part[2][lane] + part[3][lane];
        float mx = lg;
#pragma unroll
        for (int o = 32; o; o >>= 1) mx = fmaxf(mx, __shfl_xor(mx, o));
        float ex = __expf(lg - mx);
        float sum = ex;
#pragma unroll
        for (int o = 32; o; o >>= 1) sum += __shfl_xor(sum, o);
        float g = ex / sum;
        float cur = g;
        float tv[TOPK]; int ti[TOPK];
        float tsum = 0.f;
#pragma unroll
        for (int k = 0; k < TOPK; ++k) {
            float vv = cur; int ii = lane;
#pragma unroll
            for (int o = 32; o; o >>= 1) {
                float vo = __shfl_xor(vv, o);
                int io = __shfl_xor(ii, o);
                if (vo > vv || (vo == vv && io < ii)) { vv = vo; ii = io; }
            }
            tv[k] = vv; ti[k] = ii; tsum += vv;
            if (lane == ii) cur = -1.f;
        }
        float gs = fmaxf(tsum, 1.1920929e-07f);
        if (lane == 0) {
#pragma unroll
            for (int k = 0; k < TOPK; ++k) {
                topi[s * TOPK + k] = ti[k];
                wts[s * TOPK + k] = tv[k] / gs;
            }
        }
    }
}

// ---------------- parallel rank-major priority / capacity assignment ----------------
__global__ __launch_bounds__(512) void k_slots(const int* __restrict__ topi, int* __restrict__ slots,
                                               int* __restrict__ counts, int* __restrict__ etok) {
    __shared__ int tl[S * TOPK];
    __shared__ int cnt[TOPK][NE];
    __shared__ int base[TOPK][NE];
    int tid = threadIdx.x;
    for (int i = tid; i < S * TOPK; i += 512) tl[i] = topi[i];
    ((int*)cnt)[tid] = 0;
    __syncthreads();
    for (int i = tid; i < S * TOPK; i += 512)
        atomicAdd(&cnt[i & 7][tl[i]], 1);
    __syncthreads();
    if (tid < NE) {
        int acc = 0;
#pragma unroll
        for (int k = 0; k < TOPK; ++k) { base[k][tid] = acc; acc += cnt[k][tid]; }
        counts[tid] = acc < CAP ? acc : CAP;
    }
    __syncthreads();
    int k = tid >> 6, e = tid & 63;
    int rank = base[k][e];
    for (int s = 0; s < S; ++s) {
        if (tl[s * TOPK + k] == e) {
            if (rank < CAP) { slots[s * TOPK + k] = rank; etok[e * CAP + rank] = s; }
            else slots[s * TOPK + k] = -1;
            rank++;
        }
    }
}

// ---------------- final combine: out = h + shared + sum_k w_k * eo[e_k, slot_k] ----------------
__global__ __launch_bounds__(256) void k_combine(const float* __restrict__ h,
                                                 const u16* __restrict__ sh,
                                                 const u16* __restrict__ eo,
                                                 const int* __restrict__ topi,
                                                 const int* __restrict__ slots,
                                                 const float* __restrict__ wts,
                                                 float* __restrict__ out) {
    int s = blockIdx.x, t = threadIdx.x;
    float w[TOPK]; int off[TOPK];
#pragma unroll
    for (int k = 0; k < TOPK; ++k) {
        int sl = slots[s * TOPK + k];
        int ee = topi[s * TOPK + k];
        w[k] = wts[s * TOPK + k];
        off[k] = (sl >= 0) ? ee * CAP + sl : -1;
    }
#pragma unroll
    for (int i = 0; i < 4; ++i) {
        int col = t + i * 256;
        float acc = h[(size_t)s * MDIM + col] + bf2f(sh[(size_t)s * MDIM + col]);
#pragma unroll
        for (int k = 0; k < TOPK; ++k)
            if (off[k] >= 0) acc += w[k] * bf2f(eo[(size_t)off[k] * MDIM + col]);
        out[(size_t)s * MDIM + col] = acc;
    }
}

extern "C" void kernel_launch(void* const* d_in, const int* in_sizes, int n_in,
                              void* d_out, int out_size, void* d_ws, size_t ws_size,
                              hipStream_t stream) {
    (void)in_sizes; (void)n_in; (void)out_size; (void)ws_size;
    const float* hidden = (const float*)d_in[0];
    const float* cosb   = (const float*)d_in[1];
    const float* sinb   = (const float*)d_in[2];
    const float* ln1_w  = (const float*)d_in[3];
    const float* ln2_w  = (const float*)d_in[4];
    const float* qkv_w  = (const float*)d_in[5];
    const float* o_w    = (const float*)d_in[6];
    const float* qn_w   = (const float*)d_in[7];
    const float* kn_w   = (const float*)d_in[8];
    const float* sgu_w  = (const float*)d_in[9];
    const float* sdn_w  = (const float*)d_in[10];
    const float* gate_w = (const float*)d_in[11];
    const float* egu_w  = (const float*)d_in[12];
    const float* edn_w  = (const float*)d_in[13];
    float* out = (float*)d_out;

    char* ws = (char*)d_ws;
    size_t off = 0;
    auto alloc = [&](size_t bytes) -> void* {
        void* p = ws + off;
        off = (off + bytes + 255) & ~(size_t)255;
        return p;
    };
    u16*   hn_hi   = (u16*)  alloc((size_t)S * MDIM * 2);
    u16*   hn_lo   = (u16*)  alloc((size_t)S * MDIM * 2);
    float* qkvb    = (float*)alloc((size_t)S * 2048 * 4);
    u16*   qhb     = (u16*)  alloc((size_t)NH * S * HD * 2);
    u16*   qlb     = (u16*)  alloc((size_t)NH * S * HD * 2);
    u16*   khb     = (u16*)  alloc((size_t)NKV * S * HD * 2);
    u16*   klb     = (u16*)  alloc((size_t)NKV * S * HD * 2);
    u16*   vhb     = (u16*)  alloc((size_t)NKV * S * HD * 2);
    u16*   vlb     = (u16*)  alloc((size_t)NKV * S * HD * 2);
    u16*   ao_hi   = (u16*)  alloc((size_t)S * MDIM * 2);
    u16*   ao_lo   = (u16*)  alloc((size_t)S * MDIM * 2);
    float* hbuf    = (float*)alloc((size_t)S * MDIM * 4);
    u16*   h2b     = (u16*)  alloc((size_t)S * MDIM * 2);
    u16*   gatedS  = (u16*)  alloc((size_t)S * FF * 2);
    u16*   sharedO = (u16*)  alloc((size_t)S * MDIM * 2);
    int*   topi    = (int*)  alloc((size_t)S * TOPK * 4);
    float* wts     = (float*)alloc((size_t)S * TOPK * 4);
    int*   slots   = (int*)  alloc((size_t)S * TOPK * 4);
    int*   counts  = (int*)  alloc((size_t)NE * 4);
    int*   etok    = (int*)  alloc((size_t)NE * CAP * 4);
    u16*   egated  = (u16*)  alloc((size_t)NE * CAP * FF * 2);
    u16*   eo      = (u16*)  alloc((size_t)NE * CAP * MDIM * 2);

    // 1. RMS norm 1 -> hn hi/lo
    k_rms1<<<dim3(S), 256, 0, stream>>>(hidden, ln1_w, hn_hi, hn_lo);
    // 2. QKV projection (3-term split)
    k_gemm_split<0><<<dim3(2048 / 64, S / 64), 256, 0, stream>>>(
        hn_hi, hn_lo, MDIM, qkv_w, 2048, qkvb, 2048, nullptr, S, MDIM);
    // 3. unpack + RoPE + q/k RMS -> pre-split bf16
    k_rope<<<dim3(S * NKV / 4), 256, 0, stream>>>(qkvb, cosb, sinb, qn_w, kn_w,
                                                  qhb, qlb, khb, klb, vhb, vlb);
    // 4. fused flash attention (3-term QK^T and PV, online softmax)
    k_attn<<<dim3(16, NH), 256, 0, stream>>>(qhb, qlb, khb, klb, vhb, vlb, ao_hi, ao_lo);
    // 5. O projection + residual -> h f32 (3-term)
    k_gemm_split<1><<<dim3(MDIM / 64, S / 64), 256, 0, stream>>>(
        ao_hi, ao_lo, MDIM, o_w, MDIM, hbuf, MDIM, hidden, S, MDIM);
    // 6. fused RMS norm 2 + router logits + top-8
    k_rms2_router<<<dim3(S), 256, 0, stream>>>(hbuf, ln2_w, gate_w, h2b, topi, wts);
    // 7. capacity / slot assignment
    k_slots<<<dim3(1), 512, 0, stream>>>(topi, slots, counts, etok);
    // 8. expert-up + shared-up merged (swiglu) -> egated / gatedS (bf16)
    k_gemm_bf<160, 64, true, false><<<dim3(FF / 64, 2, NE + 4), 256, 0, stream>>>(
        h2b, MDIM, 0, egu_w, (long)MDIM * 2 * FF, 2 * FF,
        egated, FF, (long)CAP * FF, MDIM, FF, counts, etok,
        h2b, sgu_w, gatedS, S);
    // 9. expert-down + shared-down merged -> eo / sharedO (bf16), XCD-affinity 1D grid
    k_gemm_bf<160, 128, false, true><<<dim3(1088, 1, 1), 256, 0, stream>>>(
        egated, FF, (long)CAP * FF, edn_w, (long)FF * MDIM, MDIM,
        eo, MDIM, (long)CAP * MDIM, FF, 0, counts, nullptr,
        gatedS, sdn_w, sharedO, S);
    // 10. combine: out = h + shared + moe
    k_combine<<<dim3(S), 256, 0, stream>>>(hbuf, sharedO, eo, topi, slots, wts, out);
}